// Round 1
// baseline (950.327 us; speedup 1.0000x reference)
//
#include <hip/hip_runtime.h>
#include <math.h>

// Problem constants
#define HWX   6400   // 80*80
#define WID   80
#define HGT   80
#define CMID  128
#define CIN   256
#define COUT  256

// Workspace layout (float offsets)
#define WS_Y    0            // (8,128,80,80)  6,553,600
#define WS_PRED 6553600      // (8,27,80,80)   1,382,400  (mask pre-sigmoided)
#define WS_Z    7936000      // (8,128,80,80)  6,553,600
#define WS_WT   14489600     // (9,128,128)    147,456  dcn_w transposed [tap][c][o]
#define WS_WOR  14637056     // (128,9,28)     32,256   off_w reordered [c][tap][o pad 28]
#define WS_BN   14669312     // s1[128] b1[128] s2[128] b2[128] s3[256] b3[256]

__device__ __forceinline__ float silu_f(float t){ return t / (1.f + __expf(-t)); }

// ---------------- prep: BN scale/bias fold + weight reorders ----------------
__global__ __launch_bounds__(256) void k0_prep(
    const float* __restrict__ dcn_w, const float* __restrict__ off_w,
    const float* __restrict__ g1, const float* __restrict__ b1, const float* __restrict__ m1, const float* __restrict__ v1,
    const float* __restrict__ g2, const float* __restrict__ b2, const float* __restrict__ m2, const float* __restrict__ v2,
    const float* __restrict__ dcn_b,
    const float* __restrict__ g3, const float* __restrict__ b3, const float* __restrict__ m3, const float* __restrict__ v3,
    float* __restrict__ wt, float* __restrict__ wor, float* __restrict__ bnw)
{
    int i = blockIdx.x * 256 + threadIdx.x;
    if (i < 9*128*128) {                       // wt[tap][c][o] = dcn_w[o][c][tap]
        int o = i & 127, c = (i >> 7) & 127, tap = i >> 14;
        wt[i] = dcn_w[(o*128 + c)*9 + tap];
    }
    if (i < 128*9*28) {                        // wor[c][tap][o(pad 28)] = off_w[o][c][tap]
        int o = i % 28; int r = i / 28; int tap = r % 9; int c = r / 9;
        wor[i] = (o < 27) ? off_w[(o*128 + c)*9 + tap] : 0.f;
    }
    if (i < 128) {
        float inv = g1[i] * rsqrtf(v1[i] + 1e-5f);
        bnw[i] = inv; bnw[128+i] = b1[i] - m1[i]*inv;
    } else if (i < 256) {
        int j = i - 128;
        float inv = g2[j] * rsqrtf(v2[j] + 1e-5f);
        bnw[256+j] = inv; bnw[384+j] = b2[j] - m2[j]*inv + inv*dcn_b[j];  // fold dcn bias
    } else if (i < 512) {
        int j = i - 256;
        float inv = g3[j] * rsqrtf(v3[j] + 1e-5f);
        bnw[512+j] = inv; bnw[768+j] = b3[j] - m3[j]*inv;
    }
}

// ---------------- k1: conv1x1 (256->128) + BN1 + SiLU ----------------
// GEMM: Y[128, 6400] = W1[128,256] * X[256,6400] per batch.
// block 256 thr: 128 oc x 64 pix tile; thread: 8 oc x 4 pix.
__global__ __launch_bounds__(256) void k1_cv1(
    const float* __restrict__ x, const float* __restrict__ w1,
    const float* __restrict__ bn, float* __restrict__ y)
{
    __shared__ __align__(16) float Xs[16][64];
    __shared__ __align__(16) float Ws[16][132];   // padded rows (528B, 16B aligned)
    int blk = blockIdx.x;
    int b = blk / 100, pix0 = (blk % 100) * 64;
    int t = threadIdx.x;
    int tx = t & 15, ty = t >> 4;                 // pix group / oc group
    float acc[8][4] = {};
    const float* xb = x + (size_t)b*CIN*HWX + pix0;

    for (int kk = 0; kk < 256; kk += 16) {
        {   // stage X chunk 16k x 64pix (coalesced float4)
            int kr = t >> 4, p4 = t & 15;
            *(float4*)&Xs[kr][p4*4] = *(const float4*)(xb + (kk + kr)*HWX + p4*4);
        }
        #pragma unroll
        for (int rep = 0; rep < 2; rep++) {       // stage W chunk transposed [k][o]
            int j = t + rep*256;
            int o = j >> 2, k4 = j & 3;
            float4 v = *(const float4*)(w1 + o*256 + kk + k4*4);
            Ws[k4*4+0][o] = v.x; Ws[k4*4+1][o] = v.y; Ws[k4*4+2][o] = v.z; Ws[k4*4+3][o] = v.w;
        }
        __syncthreads();
        #pragma unroll
        for (int kr = 0; kr < 16; kr++) {
            float4 xv = *(const float4*)&Xs[kr][tx*4];
            float4 wa = *(const float4*)&Ws[kr][ty*8];
            float4 wb = *(const float4*)&Ws[kr][ty*8+4];
            float w8[8] = {wa.x,wa.y,wa.z,wa.w,wb.x,wb.y,wb.z,wb.w};
            float xp[4] = {xv.x,xv.y,xv.z,xv.w};
            #pragma unroll
            for (int i = 0; i < 8; i++)
                #pragma unroll
                for (int j = 0; j < 4; j++) acc[i][j] += w8[i]*xp[j];
        }
        __syncthreads();
    }
    int o0 = ty*8;
    float* yb = y + (size_t)b*CMID*HWX + pix0 + tx*4;
    #pragma unroll
    for (int i = 0; i < 8; i++) {
        int o = o0 + i; float s = bn[o], be = bn[128+o];
        float4 r;
        r.x = silu_f(acc[i][0]*s+be); r.y = silu_f(acc[i][1]*s+be);
        r.z = silu_f(acc[i][2]*s+be); r.w = silu_f(acc[i][3]*s+be);
        *(float4*)(yb + o*HWX) = r;
    }
}

// ---------------- k2: 3x3 conv (128->27) + bias; mask channels sigmoided ----------------
// block = 16x16 pixel tile, 1 thread/pixel, acc[28]; weights via uniform (scalar-cached) loads.
__global__ __launch_bounds__(256) void k2_off(
    const float* __restrict__ y, const float* __restrict__ wor,
    const float* __restrict__ ob, float* __restrict__ pred)
{
    __shared__ float Ys[4][18][18];
    int blk = blockIdx.x;                  // 8 * 25
    int b = blk / 25, tile = blk % 25;
    int ty0 = (tile / 5) * 16, tx0 = (tile % 5) * 16;
    int t = threadIdx.x;
    int px = t & 15, py = t >> 4;
    float acc[28];
    #pragma unroll
    for (int o = 0; o < 27; o++) acc[o] = ob[o];
    acc[27] = 0.f;
    const float* yb = y + (size_t)b*CMID*HWX;

    for (int cb = 0; cb < 128; cb += 4) {
        __syncthreads();
        for (int i = t; i < 4*18*18; i += 256) {   // halo stage, zero-pad
            int c = i / 324, r = (i % 324) / 18, col = i % 18;
            int gy = ty0 + r - 1, gx = tx0 + col - 1;
            float v = 0.f;
            if (gy >= 0 && gy < HGT && gx >= 0 && gx < WID) v = yb[(cb+c)*HWX + gy*WID + gx];
            Ys[c][r][col] = v;
        }
        __syncthreads();
        #pragma unroll
        for (int c = 0; c < 4; c++) {
            #pragma unroll
            for (int tap = 0; tap < 9; tap++) {
                float yv = Ys[c][py + tap/3][px + tap%3];
                const float4* wp4 = (const float4*)(wor + ((cb + c)*9 + tap)*28);
                #pragma unroll
                for (int q = 0; q < 7; q++) {
                    float4 wv = wp4[q];
                    acc[q*4+0] += yv*wv.x; acc[q*4+1] += yv*wv.y;
                    acc[q*4+2] += yv*wv.z; acc[q*4+3] += yv*wv.w;
                }
            }
        }
    }
    int pix = (ty0 + py)*WID + (tx0 + px);
    float* pb = pred + (size_t)b*27*HWX + pix;
    #pragma unroll
    for (int o = 0; o < 27; o++) {
        float v = acc[o];
        if (o >= 18) v = 1.f / (1.f + __expf(-v));   // pre-sigmoid mask
        pb[o*HWX] = v;
    }
}

// ---------------- k3: deformable conv + BN2 + SiLU ----------------
// block: 32 pixels x 128 oc. Per tap: bilinear-sample S[128c][32p] into LDS,
// then register-tiled GEMM acc[4oc][4pix] over c with staged W chunks.
__global__ __launch_bounds__(256) void k3_dcn(
    const float* __restrict__ y, const float* __restrict__ pred,
    const float* __restrict__ wt, const float* __restrict__ bn, float* __restrict__ z)
{
    __shared__ __align__(16) float S[128][32];
    __shared__ __align__(16) float Wt_s[32][128];
    __shared__ int   sidx[32][4];
    __shared__ float swgt[32][4];
    int blk = blockIdx.x;                  // 1600
    int b = blk / 200, pix0 = (blk % 200) * 32;
    int t = threadIdx.x;
    int tx = t & 7, ty = t >> 3;           // p0 = tx*4, o0 = ty*4
    float acc[4][4] = {};
    const float* yb = y + (size_t)b*CMID*HWX;
    const float* pb = pred + (size_t)b*27*HWX;

    for (int tap = 0; tap < 9; tap++) {
        __syncthreads();                   // prev tap's GEMM done before overwriting params/S
        if (t < 32) {                      // per-pixel bilinear params
            int pix = pix0 + t;
            int h = pix / WID, w = pix % WID;
            float dy = pb[(2*tap)*HWX + pix];
            float dx = pb[(2*tap+1)*HWX + pix];
            float mk = pb[(18+tap)*HWX + pix];
            float pyf = (float)(h - 1 + tap/3) + dy;
            float pxf = (float)(w - 1 + tap%3) + dx;
            float y0f = floorf(pyf), x0f = floorf(pxf);
            float wy1 = pyf - y0f, wx1 = pxf - x0f;
            int iy0 = (int)y0f, ix0 = (int)x0f;
            int iy1 = iy0 + 1,  ix1 = ix0 + 1;
            float vy0 = (iy0 >= 0 && iy0 < HGT) ? 1.f : 0.f;
            float vy1 = (iy1 >= 0 && iy1 < HGT) ? 1.f : 0.f;
            float vx0 = (ix0 >= 0 && ix0 < WID) ? 1.f : 0.f;
            float vx1 = (ix1 >= 0 && ix1 < WID) ? 1.f : 0.f;
            int cy0 = min(max(iy0,0),HGT-1), cy1 = min(max(iy1,0),HGT-1);
            int cx0 = min(max(ix0,0),WID-1), cx1 = min(max(ix1,0),WID-1);
            sidx[t][0] = cy0*WID+cx0; sidx[t][1] = cy0*WID+cx1;
            sidx[t][2] = cy1*WID+cx0; sidx[t][3] = cy1*WID+cx1;
            swgt[t][0] = (1.f-wy1)*(1.f-wx1)*mk*vy0*vx0;
            swgt[t][1] = (1.f-wy1)*wx1*mk*vy0*vx1;
            swgt[t][2] = wy1*(1.f-wx1)*mk*vy1*vx0;
            swgt[t][3] = wy1*wx1*mk*vy1*vx1;
        }
        __syncthreads();
        #pragma unroll
        for (int i = 0; i < 16; i++) {     // build S: 4096 samples, 16/thread
            int lin = t + i*256;
            int pix = lin & 31, c = lin >> 5;
            const float* cb2 = yb + c*HWX;
            S[c][pix] = swgt[pix][0]*cb2[sidx[pix][0]] + swgt[pix][1]*cb2[sidx[pix][1]]
                      + swgt[pix][2]*cb2[sidx[pix][2]] + swgt[pix][3]*cb2[sidx[pix][3]];
        }
        const float* wtap = wt + tap*128*128;
        for (int cc = 0; cc < 4; cc++) {
            __syncthreads();               // S ready (cc=0) / prev W chunk consumed
            #pragma unroll
            for (int r = 0; r < 4; r++) {  // stage Wt_s[32][128] coalesced
                int j = t + r*256;
                int c = j >> 5, q = j & 31;
                *(float4*)&Wt_s[c][q*4] = *(const float4*)(wtap + (cc*32 + c)*128 + q*4);
            }
            __syncthreads();
            #pragma unroll
            for (int c = 0; c < 32; c++) {
                float4 sv = *(const float4*)&S[cc*32 + c][tx*4];
                float4 wv = *(const float4*)&Wt_s[c][ty*4];
                float sp[4] = {sv.x,sv.y,sv.z,sv.w};
                float wp[4] = {wv.x,wv.y,wv.z,wv.w};
                #pragma unroll
                for (int i = 0; i < 4; i++)
                    #pragma unroll
                    for (int j2 = 0; j2 < 4; j2++) acc[i][j2] += wp[i]*sp[j2];
            }
        }
    }
    int o0 = ty*4;
    float* zb = z + (size_t)b*CMID*HWX + pix0 + tx*4;
    #pragma unroll
    for (int i = 0; i < 4; i++) {
        int o = o0 + i; float s = bn[256+o], be = bn[384+o];
        float4 r;
        r.x = silu_f(acc[i][0]*s+be); r.y = silu_f(acc[i][1]*s+be);
        r.z = silu_f(acc[i][2]*s+be); r.w = silu_f(acc[i][3]*s+be);
        *(float4*)(zb + o*HWX) = r;
    }
}

// ---------------- k4: conv1x1 (128->256) + BN3 + SiLU + residual ----------------
__global__ __launch_bounds__(256) void k4_cv3(
    const float* __restrict__ z, const float* __restrict__ w3,
    const float* __restrict__ bn, const float* __restrict__ x, float* __restrict__ out)
{
    __shared__ __align__(16) float Zs[16][64];
    __shared__ __align__(16) float Ws[16][132];
    int blk = blockIdx.x;                  // 8*100*2
    int half = blk & 1, blk2 = blk >> 1;
    int b = blk2 / 100, pix0 = (blk2 % 100) * 64;
    int t = threadIdx.x;
    int tx = t & 15, ty = t >> 4;
    float acc[8][4] = {};
    const float* zb = z + (size_t)b*CMID*HWX + pix0;
    const float* w3h = w3 + half*128*CMID;

    for (int kk = 0; kk < 128; kk += 16) {
        {
            int kr = t >> 4, p4 = t & 15;
            *(float4*)&Zs[kr][p4*4] = *(const float4*)(zb + (kk + kr)*HWX + p4*4);
        }
        #pragma unroll
        for (int rep = 0; rep < 2; rep++) {
            int j = t + rep*256;
            int o = j >> 2, k4 = j & 3;
            float4 v = *(const float4*)(w3h + o*CMID + kk + k4*4);
            Ws[k4*4+0][o] = v.x; Ws[k4*4+1][o] = v.y; Ws[k4*4+2][o] = v.z; Ws[k4*4+3][o] = v.w;
        }
        __syncthreads();
        #pragma unroll
        for (int kr = 0; kr < 16; kr++) {
            float4 xv = *(const float4*)&Zs[kr][tx*4];
            float4 wa = *(const float4*)&Ws[kr][ty*8];
            float4 wb = *(const float4*)&Ws[kr][ty*8+4];
            float w8[8] = {wa.x,wa.y,wa.z,wa.w,wb.x,wb.y,wb.z,wb.w};
            float xp[4] = {xv.x,xv.y,xv.z,xv.w};
            #pragma unroll
            for (int i = 0; i < 8; i++)
                #pragma unroll
                for (int j = 0; j < 4; j++) acc[i][j] += w8[i]*xp[j];
        }
        __syncthreads();
    }
    int o0 = ty*8;
    const float* xb = x + (size_t)b*COUT*HWX + (size_t)half*128*HWX + pix0 + tx*4;
    float* ob = out + (size_t)b*COUT*HWX + (size_t)half*128*HWX + pix0 + tx*4;
    #pragma unroll
    for (int i = 0; i < 8; i++) {
        int og = half*128 + o0 + i;
        float s = bn[512+og], be = bn[768+og];
        float4 xr = *(const float4*)(xb + (o0+i)*HWX);
        float4 r;
        r.x = xr.x + silu_f(acc[i][0]*s+be); r.y = xr.y + silu_f(acc[i][1]*s+be);
        r.z = xr.z + silu_f(acc[i][2]*s+be); r.w = xr.w + silu_f(acc[i][3]*s+be);
        *(float4*)(ob + (o0+i)*HWX) = r;
    }
}

extern "C" void kernel_launch(void* const* d_in, const int* in_sizes, int n_in,
                              void* d_out, int out_size, void* d_ws, size_t ws_size,
                              hipStream_t stream) {
    const float* x     = (const float*)d_in[0];
    const float* cv1_w = (const float*)d_in[1];
    const float* bn1_g = (const float*)d_in[2];
    const float* bn1_b = (const float*)d_in[3];
    const float* bn1_m = (const float*)d_in[4];
    const float* bn1_v = (const float*)d_in[5];
    const float* off_w = (const float*)d_in[6];
    const float* off_b = (const float*)d_in[7];
    const float* dcn_w = (const float*)d_in[8];
    const float* dcn_b = (const float*)d_in[9];
    const float* bn2_g = (const float*)d_in[10];
    const float* bn2_b = (const float*)d_in[11];
    const float* bn2_m = (const float*)d_in[12];
    const float* bn2_v = (const float*)d_in[13];
    const float* cv3_w = (const float*)d_in[14];
    const float* bn3_g = (const float*)d_in[15];
    const float* bn3_b = (const float*)d_in[16];
    const float* bn3_m = (const float*)d_in[17];
    const float* bn3_v = (const float*)d_in[18];

    float* ws   = (float*)d_ws;
    float* Y    = ws + WS_Y;
    float* PRED = ws + WS_PRED;
    float* Z    = ws + WS_Z;
    float* WT   = ws + WS_WT;
    float* WOR  = ws + WS_WOR;
    float* BN   = ws + WS_BN;

    hipLaunchKernelGGL(k0_prep, dim3(576), dim3(256), 0, stream,
        dcn_w, off_w, bn1_g, bn1_b, bn1_m, bn1_v,
        bn2_g, bn2_b, bn2_m, bn2_v, dcn_b,
        bn3_g, bn3_b, bn3_m, bn3_v, WT, WOR, BN);
    hipLaunchKernelGGL(k1_cv1, dim3(800), dim3(256), 0, stream, x, cv1_w, BN, Y);
    hipLaunchKernelGGL(k2_off, dim3(200), dim3(256), 0, stream, Y, WOR, off_b, PRED);
    hipLaunchKernelGGL(k3_dcn, dim3(1600), dim3(256), 0, stream, Y, PRED, WT, BN, Z);
    hipLaunchKernelGGL(k4_cv3, dim3(1600), dim3(256), 0, stream, Z, cv3_w, BN, x, (float*)d_out);
}

// Round 2
// 599.513 us; speedup vs baseline: 1.5852x; 1.5852x over previous
//
#include <hip/hip_runtime.h>
#include <math.h>

// Problem constants
#define HWX   6400   // 80*80
#define WID   80
#define HGT   80
#define CMID  128
#define CIN   256
#define COUT  256

// Workspace layout (float offsets)
#define WS_PRED 0            // (8,27,80,80)   1,382,400  (mask pre-sigmoided)
#define WS_Z    1382400      // (8,128,80,80)  6,553,600
#define WS_WOR  7936000      // (128,9,28)     32,256   off_w reordered [c][tap][o pad 28]
#define WS_BN   7968256      // s1[128] b1[128] s2[128] b2[128] s3[256] b3[256]
#define WS_Y2   7969280      // (8,6400,128) bf16 NHWC = 3,276,800 floats of storage
#define WS_WPK  11246080     // dcn_w prepacked MFMA A-frags: 73,728 dwords

typedef float floatx16 __attribute__((ext_vector_type(16)));
typedef short shortx8  __attribute__((ext_vector_type(8)));

union U8 { uint32_t u[4]; shortx8 s; };

__device__ __forceinline__ float silu_f(float t){ return t / (1.f + __expf(-t)); }
__device__ __forceinline__ float bf16lo(uint32_t u){ return __uint_as_float(u << 16); }
__device__ __forceinline__ float bf16hi(uint32_t u){ return __uint_as_float(u & 0xffff0000u); }
__device__ __forceinline__ uint32_t f2bf(float f){           // RNE fp32->bf16
    uint32_t u = __float_as_uint(f);
    return (u + 0x7fffu + ((u >> 16) & 1u)) >> 16;
}

// ---------------- prep: BN fold + weight reorders + MFMA weight prepack ----------------
__global__ __launch_bounds__(256) void k0_prep(
    const float* __restrict__ dcn_w, const float* __restrict__ off_w,
    const float* __restrict__ g1, const float* __restrict__ b1, const float* __restrict__ m1, const float* __restrict__ v1,
    const float* __restrict__ g2, const float* __restrict__ b2, const float* __restrict__ m2, const float* __restrict__ v2,
    const float* __restrict__ dcn_b,
    const float* __restrict__ g3, const float* __restrict__ b3, const float* __restrict__ m3, const float* __restrict__ v3,
    uint32_t* __restrict__ wpk, float* __restrict__ wor, float* __restrict__ bnw)
{
    int i = blockIdx.x * 256 + threadIdx.x;
    if (i < 4*9*8*256) {
        // wpk layout: ((g*9 + tap)*8 + s)*256 + lane*4 + j  (dwords)
        // lane's A frag: oc = g*32 + (lane&31); k(c) = s*16 + (lane>>5)*8 + 2j (+1 in hi)
        int j = i & 3, lane = (i >> 2) & 63, s = (i >> 8) & 7;
        int r2 = i >> 11; int tap = r2 % 9, g = r2 / 9;
        int oc = g*32 + (lane & 31);
        int c  = s*16 + ((lane >> 5) << 3) + 2*j;
        float lo = dcn_w[(oc*128 + c)*9 + tap];
        float hi = dcn_w[(oc*128 + c + 1)*9 + tap];
        wpk[i] = f2bf(lo) | (f2bf(hi) << 16);
    }
    if (i < 128*9*28) {                        // wor[c][tap][o(pad 28)] = off_w[o][c][tap]
        int o = i % 28; int r = i / 28; int tap = r % 9; int c = r / 9;
        wor[i] = (o < 27) ? off_w[(o*128 + c)*9 + tap] : 0.f;
    }
    if (i < 128) {
        float inv = g1[i] * rsqrtf(v1[i] + 1e-5f);
        bnw[i] = inv; bnw[128+i] = b1[i] - m1[i]*inv;
    } else if (i < 256) {
        int j = i - 128;
        float inv = g2[j] * rsqrtf(v2[j] + 1e-5f);
        bnw[256+j] = inv; bnw[384+j] = b2[j] - m2[j]*inv + inv*dcn_b[j];  // fold dcn bias
    } else if (i < 512) {
        int j = i - 256;
        float inv = g3[j] * rsqrtf(v3[j] + 1e-5f);
        bnw[512+j] = inv; bnw[768+j] = b3[j] - m3[j]*inv;
    }
}

// ---------------- k1: conv1x1 (256->128) + BN1 + SiLU -> Y2 bf16 NHWC ----------------
__global__ __launch_bounds__(256) void k1_cv1(
    const float* __restrict__ x, const float* __restrict__ w1,
    const float* __restrict__ bn, uint32_t* __restrict__ y2)
{
    __shared__ __align__(16) float Xs[16][64];
    __shared__ __align__(16) float Ws[16][132];
    int blk = blockIdx.x;
    int b = blk / 100, pix0 = (blk % 100) * 64;
    int t = threadIdx.x;
    int tx = t & 15, ty = t >> 4;                 // pix group / oc group
    float acc[8][4] = {};
    const float* xb = x + (size_t)b*CIN*HWX + pix0;

    for (int kk = 0; kk < 256; kk += 16) {
        {
            int kr = t >> 4, p4 = t & 15;
            *(float4*)&Xs[kr][p4*4] = *(const float4*)(xb + (kk + kr)*HWX + p4*4);
        }
        #pragma unroll
        for (int rep = 0; rep < 2; rep++) {
            int j = t + rep*256;
            int o = j >> 2, k4 = j & 3;
            float4 v = *(const float4*)(w1 + o*256 + kk + k4*4);
            Ws[k4*4+0][o] = v.x; Ws[k4*4+1][o] = v.y; Ws[k4*4+2][o] = v.z; Ws[k4*4+3][o] = v.w;
        }
        __syncthreads();
        #pragma unroll
        for (int kr = 0; kr < 16; kr++) {
            float4 xv = *(const float4*)&Xs[kr][tx*4];
            float4 wa = *(const float4*)&Ws[kr][ty*8];
            float4 wb = *(const float4*)&Ws[kr][ty*8+4];
            float w8[8] = {wa.x,wa.y,wa.z,wa.w,wb.x,wb.y,wb.z,wb.w};
            float xp[4] = {xv.x,xv.y,xv.z,xv.w};
            #pragma unroll
            for (int i = 0; i < 8; i++)
                #pragma unroll
                for (int j = 0; j < 4; j++) acc[i][j] += w8[i]*xp[j];
        }
        __syncthreads();
    }
    int o0 = ty*8;
    float vals[8][4];
    #pragma unroll
    for (int i = 0; i < 8; i++) {
        int o = o0 + i; float s = bn[o], be = bn[128+o];
        #pragma unroll
        for (int j = 0; j < 4; j++) vals[i][j] = silu_f(acc[i][j]*s + be);
    }
    uint32_t* y2b = y2 + (size_t)b*HWX*64;
    int pixb = pix0 + tx*4;
    #pragma unroll
    for (int j = 0; j < 4; j++) {
        uint32_t d0 = f2bf(vals[0][j]) | (f2bf(vals[1][j]) << 16);
        uint32_t d1 = f2bf(vals[2][j]) | (f2bf(vals[3][j]) << 16);
        uint32_t d2 = f2bf(vals[4][j]) | (f2bf(vals[5][j]) << 16);
        uint32_t d3 = f2bf(vals[6][j]) | (f2bf(vals[7][j]) << 16);
        uint4 q = make_uint4(d0, d1, d2, d3);
        *(uint4*)(y2b + (size_t)(pixb + j)*64 + ty*4) = q;
    }
}

// ---------------- k2: 3x3 conv (128->27) + bias; mask sigmoided; reads Y2 bf16 NHWC ----------------
__global__ __launch_bounds__(256) void k2_off(
    const uint32_t* __restrict__ y2, const float* __restrict__ wor,
    const float* __restrict__ ob, float* __restrict__ pred)
{
    __shared__ float Ys[4][18][18];
    int blk = blockIdx.x;                  // 8 * 25
    int b = blk / 25, tile = blk % 25;
    int ty0 = (tile / 5) * 16, tx0 = (tile % 5) * 16;
    int t = threadIdx.x;
    int px = t & 15, py = t >> 4;
    float acc[28];
    #pragma unroll
    for (int o = 0; o < 27; o++) acc[o] = ob[o];
    acc[27] = 0.f;
    const uint32_t* yb = y2 + (size_t)b*HWX*64;

    for (int cb = 0; cb < 128; cb += 4) {
        __syncthreads();
        for (int i = t; i < 324; i += 256) {   // halo stage, 4 channels per entry
            int r = i / 18, col = i % 18;
            int gy = ty0 + r - 1, gx = tx0 + col - 1;
            float v0=0.f, v1=0.f, v2=0.f, v3=0.f;
            if (gy >= 0 && gy < HGT && gx >= 0 && gx < WID) {
                const uint32_t* p = yb + (size_t)(gy*WID + gx)*64 + (cb >> 1);
                uint32_t a = p[0], b2 = p[1];
                v0 = bf16lo(a); v1 = bf16hi(a); v2 = bf16lo(b2); v3 = bf16hi(b2);
            }
            Ys[0][r][col] = v0; Ys[1][r][col] = v1; Ys[2][r][col] = v2; Ys[3][r][col] = v3;
        }
        __syncthreads();
        #pragma unroll
        for (int c = 0; c < 4; c++) {
            #pragma unroll
            for (int tap = 0; tap < 9; tap++) {
                float yv = Ys[c][py + tap/3][px + tap%3];
                const float4* wp4 = (const float4*)(wor + ((cb + c)*9 + tap)*28);
                #pragma unroll
                for (int q = 0; q < 7; q++) {
                    float4 wv = wp4[q];
                    acc[q*4+0] += yv*wv.x; acc[q*4+1] += yv*wv.y;
                    acc[q*4+2] += yv*wv.z; acc[q*4+3] += yv*wv.w;
                }
            }
        }
    }
    int pix = (ty0 + py)*WID + (tx0 + px);
    float* pb = pred + (size_t)b*27*HWX + pix;
    #pragma unroll
    for (int o = 0; o < 27; o++) {
        float v = acc[o];
        if (o >= 18) v = 1.f / (1.f + __expf(-v));   // pre-sigmoid mask
        pb[o*HWX] = v;
    }
}

// ---------------- k3: deformable conv (MFMA bf16) + BN2 + SiLU ----------------
// block: 4 waves, tile 128 oc x 32 pix. Per tap: coalesced NHWC gather ->
// S2[64 c2][33 pix] bf16x2 in LDS; per wave 8x mfma_f32_32x32x16_bf16 with
// A streamed prepacked from global (L2-resident).
#define S2S 33
__global__ __launch_bounds__(256) void k3_dcn(
    const uint32_t* __restrict__ y2, const float* __restrict__ pred,
    const uint32_t* __restrict__ wpk, const float* __restrict__ bn, float* __restrict__ z)
{
    __shared__ uint32_t S2[64*S2S];
    __shared__ int   sidx[32][4];
    __shared__ float swgt[32][4];
    int blk = blockIdx.x;                  // 1600
    int b = blk / 200, pix0 = (blk % 200) * 32;
    int t = threadIdx.x;
    int lane = t & 63, w = t >> 6;
    const float* pb = pred + (size_t)b*27*HWX;
    const uint32_t* yb = y2 + (size_t)b*HWX*64;
    floatx16 acc = {};

    for (int tap = 0; tap < 9; tap++) {
        __syncthreads();                   // prev tap's GEMM done
        if (t < 32) {                      // per-pixel bilinear params
            int pix = pix0 + t;
            int h = pix / WID, wq = pix % WID;
            float dy = pb[(2*tap)*HWX + pix];
            float dx = pb[(2*tap+1)*HWX + pix];
            float mk = pb[(18+tap)*HWX + pix];
            float pyf = (float)(h - 1 + tap/3) + dy;
            float pxf = (float)(wq - 1 + tap%3) + dx;
            float y0f = floorf(pyf), x0f = floorf(pxf);
            float wy1 = pyf - y0f, wx1 = pxf - x0f;
            int iy0 = (int)y0f, ix0 = (int)x0f;
            int iy1 = iy0 + 1,  ix1 = ix0 + 1;
            float vy0 = (iy0 >= 0 && iy0 < HGT) ? 1.f : 0.f;
            float vy1 = (iy1 >= 0 && iy1 < HGT) ? 1.f : 0.f;
            float vx0 = (ix0 >= 0 && ix0 < WID) ? 1.f : 0.f;
            float vx1 = (ix1 >= 0 && ix1 < WID) ? 1.f : 0.f;
            int cy0 = min(max(iy0,0),HGT-1), cy1 = min(max(iy1,0),HGT-1);
            int cx0 = min(max(ix0,0),WID-1), cx1 = min(max(ix1,0),WID-1);
            sidx[t][0] = cy0*WID+cx0; sidx[t][1] = cy0*WID+cx1;
            sidx[t][2] = cy1*WID+cx0; sidx[t][3] = cy1*WID+cx1;
            swgt[t][0] = (1.f-wy1)*(1.f-wx1)*mk*vy0*vx0;
            swgt[t][1] = (1.f-wy1)*wx1*mk*vy0*vx1;
            swgt[t][2] = wy1*(1.f-wx1)*mk*vy1*vx0;
            swgt[t][3] = wy1*wx1*mk*vy1*vx1;
        }
        __syncthreads();
        // build S2: per pass, whole wave = one pixel, lane = c2 (coalesced 256B/corner)
        #pragma unroll
        for (int p = 0; p < 8; p++) {
            int pix = p*4 + w;
            int i0 = sidx[pix][0], i1 = sidx[pix][1], i2 = sidx[pix][2], i3 = sidx[pix][3];
            float w0 = swgt[pix][0], w1 = swgt[pix][1], w2 = swgt[pix][2], w3 = swgt[pix][3];
            uint32_t u0 = yb[i0*64 + lane], u1 = yb[i1*64 + lane];
            uint32_t u2 = yb[i2*64 + lane], u3 = yb[i3*64 + lane];
            float lo = w0*bf16lo(u0) + w1*bf16lo(u1) + w2*bf16lo(u2) + w3*bf16lo(u3);
            float hi = w0*bf16hi(u0) + w1*bf16hi(u1) + w2*bf16hi(u2) + w3*bf16hi(u3);
            S2[lane*S2S + pix] = f2bf(lo) | (f2bf(hi) << 16);
        }
        __syncthreads();
        // GEMM for this tap: 8 K-steps of 32x32x16
        const uint32_t* wp = wpk + (size_t)((w*9 + tap)*8)*256 + lane*4;
        int kb = (lane >> 5) * 4;          // c2 sub-offset
        int pixl = lane & 31;
        #pragma unroll
        for (int s = 0; s < 8; s++) {
            U8 a, bf;
            const uint32_t* wps = wp + s*256;
            a.u[0] = wps[0]; a.u[1] = wps[1]; a.u[2] = wps[2]; a.u[3] = wps[3];
            int c2b = s*8 + kb;
            bf.u[0] = S2[(c2b+0)*S2S + pixl];
            bf.u[1] = S2[(c2b+1)*S2S + pixl];
            bf.u[2] = S2[(c2b+2)*S2S + pixl];
            bf.u[3] = S2[(c2b+3)*S2S + pixl];
            acc = __builtin_amdgcn_mfma_f32_32x32x16_bf16(a.s, bf.s, acc, 0, 0, 0);
        }
    }
    // epilogue: D layout col=lane&31 (pix), row=(r&3)+8*(r>>2)+4*(lane>>5)
    int pixg = pix0 + (lane & 31);
    float* zb = z + (size_t)b*CMID*HWX + pixg;
    #pragma unroll
    for (int r = 0; r < 16; r++) {
        int oc = w*32 + (r & 3) + 8*(r >> 2) + 4*(lane >> 5);
        float sc = bn[256+oc], be = bn[384+oc];
        zb[oc*HWX] = silu_f(acc[r]*sc + be);
    }
}

// ---------------- k4: conv1x1 (128->256) + BN3 + SiLU + residual ----------------
__global__ __launch_bounds__(256) void k4_cv3(
    const float* __restrict__ z, const float* __restrict__ w3,
    const float* __restrict__ bn, const float* __restrict__ x, float* __restrict__ out)
{
    __shared__ __align__(16) float Zs[16][64];
    __shared__ __align__(16) float Ws[16][132];
    int blk = blockIdx.x;                  // 8*100*2
    int half = blk & 1, blk2 = blk >> 1;
    int b = blk2 / 100, pix0 = (blk2 % 100) * 64;
    int t = threadIdx.x;
    int tx = t & 15, ty = t >> 4;
    float acc[8][4] = {};
    const float* zb = z + (size_t)b*CMID*HWX + pix0;
    const float* w3h = w3 + half*128*CMID;

    for (int kk = 0; kk < 128; kk += 16) {
        {
            int kr = t >> 4, p4 = t & 15;
            *(float4*)&Zs[kr][p4*4] = *(const float4*)(zb + (kk + kr)*HWX + p4*4);
        }
        #pragma unroll
        for (int rep = 0; rep < 2; rep++) {
            int j = t + rep*256;
            int o = j >> 2, k4 = j & 3;
            float4 v = *(const float4*)(w3h + o*CMID + kk + k4*4);
            Ws[k4*4+0][o] = v.x; Ws[k4*4+1][o] = v.y; Ws[k4*4+2][o] = v.z; Ws[k4*4+3][o] = v.w;
        }
        __syncthreads();
        #pragma unroll
        for (int kr = 0; kr < 16; kr++) {
            float4 xv = *(const float4*)&Zs[kr][tx*4];
            float4 wa = *(const float4*)&Ws[kr][ty*8];
            float4 wb = *(const float4*)&Ws[kr][ty*8+4];
            float w8[8] = {wa.x,wa.y,wa.z,wa.w,wb.x,wb.y,wb.z,wb.w};
            float xp[4] = {xv.x,xv.y,xv.z,xv.w};
            #pragma unroll
            for (int i = 0; i < 8; i++)
                #pragma unroll
                for (int j = 0; j < 4; j++) acc[i][j] += w8[i]*xp[j];
        }
        __syncthreads();
    }
    int o0 = ty*8;
    const float* xb = x + (size_t)b*COUT*HWX + (size_t)half*128*HWX + pix0 + tx*4;
    float* ob = out + (size_t)b*COUT*HWX + (size_t)half*128*HWX + pix0 + tx*4;
    #pragma unroll
    for (int i = 0; i < 8; i++) {
        int og = half*128 + o0 + i;
        float s = bn[512+og], be = bn[768+og];
        float4 xr = *(const float4*)(xb + (o0+i)*HWX);
        float4 r;
        r.x = xr.x + silu_f(acc[i][0]*s+be); r.y = xr.y + silu_f(acc[i][1]*s+be);
        r.z = xr.z + silu_f(acc[i][2]*s+be); r.w = xr.w + silu_f(acc[i][3]*s+be);
        *(float4*)(ob + (o0+i)*HWX) = r;
    }
}

extern "C" void kernel_launch(void* const* d_in, const int* in_sizes, int n_in,
                              void* d_out, int out_size, void* d_ws, size_t ws_size,
                              hipStream_t stream) {
    const float* x     = (const float*)d_in[0];
    const float* cv1_w = (const float*)d_in[1];
    const float* bn1_g = (const float*)d_in[2];
    const float* bn1_b = (const float*)d_in[3];
    const float* bn1_m = (const float*)d_in[4];
    const float* bn1_v = (const float*)d_in[5];
    const float* off_w = (const float*)d_in[6];
    const float* off_b = (const float*)d_in[7];
    const float* dcn_w = (const float*)d_in[8];
    const float* dcn_b = (const float*)d_in[9];
    const float* bn2_g = (const float*)d_in[10];
    const float* bn2_b = (const float*)d_in[11];
    const float* bn2_m = (const float*)d_in[12];
    const float* bn2_v = (const float*)d_in[13];
    const float* cv3_w = (const float*)d_in[14];
    const float* bn3_g = (const float*)d_in[15];
    const float* bn3_b = (const float*)d_in[16];
    const float* bn3_m = (const float*)d_in[17];
    const float* bn3_v = (const float*)d_in[18];

    float* ws   = (float*)d_ws;
    float*    PRED = ws + WS_PRED;
    float*    Z    = ws + WS_Z;
    float*    WOR  = ws + WS_WOR;
    float*    BN   = ws + WS_BN;
    uint32_t* Y2   = (uint32_t*)(ws + WS_Y2);
    uint32_t* WPK  = (uint32_t*)(ws + WS_WPK);

    hipLaunchKernelGGL(k0_prep, dim3(288), dim3(256), 0, stream,
        dcn_w, off_w, bn1_g, bn1_b, bn1_m, bn1_v,
        bn2_g, bn2_b, bn2_m, bn2_v, dcn_b,
        bn3_g, bn3_b, bn3_m, bn3_v, WPK, WOR, BN);
    hipLaunchKernelGGL(k1_cv1, dim3(800), dim3(256), 0, stream, x, cv1_w, BN, Y2);
    hipLaunchKernelGGL(k2_off, dim3(200), dim3(256), 0, stream, Y2, WOR, off_b, PRED);
    hipLaunchKernelGGL(k3_dcn, dim3(1600), dim3(256), 0, stream, Y2, PRED, WPK, BN, Z);
    hipLaunchKernelGGL(k4_cv3, dim3(1600), dim3(256), 0, stream, Z, cv3_w, BN, x, (float*)d_out);
}

// Round 3
// 316.685 us; speedup vs baseline: 3.0009x; 1.8931x over previous
//
#include <hip/hip_runtime.h>
#include <math.h>

// Problem constants
#define HWX   6400   // 80*80
#define WID   80
#define HGT   80
#define CMID  128
#define CIN   256
#define COUT  256

// Workspace layout (float offsets)
#define WS_PRED 0            // (8,27,80,80)   1,382,400  (mask pre-sigmoided)
#define WS_Z    1382400      // (8,128,80,80)  6,553,600
#define WS_BN   7936000      // s1[128] b1[128] s2[128] b2[128] s3[256] b3[256] = 1024
#define WS_Y2   7937024      // (8,6400,128) bf16 NHWC = 3,276,800 dword slots
#define WS_WPK  11213824     // dcn_w prepacked MFMA A-frags: 73,728 dwords
#define WS_WPO  11287552     // off_w prepacked MFMA A-frags: 18,432 dwords

typedef float floatx16 __attribute__((ext_vector_type(16)));
typedef short shortx8  __attribute__((ext_vector_type(8)));

union U8 { uint32_t u[4]; shortx8 s; };

__device__ __forceinline__ float silu_f(float t){ return t / (1.f + __expf(-t)); }
__device__ __forceinline__ float bf16lo(uint32_t u){ return __uint_as_float(u << 16); }
__device__ __forceinline__ float bf16hi(uint32_t u){ return __uint_as_float(u & 0xffff0000u); }
__device__ __forceinline__ uint32_t f2bf(float f){           // RNE fp32->bf16
    uint32_t u = __float_as_uint(f);
    return (u + 0x7fffu + ((u >> 16) & 1u)) >> 16;
}

// ---------------- prep: BN fold + MFMA weight prepacks ----------------
__global__ __launch_bounds__(256) void k0_prep(
    const float* __restrict__ dcn_w, const float* __restrict__ off_w,
    const float* __restrict__ g1, const float* __restrict__ b1, const float* __restrict__ m1, const float* __restrict__ v1,
    const float* __restrict__ g2, const float* __restrict__ b2, const float* __restrict__ m2, const float* __restrict__ v2,
    const float* __restrict__ dcn_b,
    const float* __restrict__ g3, const float* __restrict__ b3, const float* __restrict__ m3, const float* __restrict__ v3,
    uint32_t* __restrict__ wpk, uint32_t* __restrict__ wpo, float* __restrict__ bnw)
{
    int i = blockIdx.x * 256 + threadIdx.x;
    if (i < 4*9*8*256) {
        // wpk layout: ((g*9 + tap)*8 + s)*256 + lane*4 + j  (dwords)
        // lane's A frag: oc = g*32 + (lane&31); k(c) = s*16 + (lane>>5)*8 + 2j (+1 in hi)
        int j = i & 3, lane = (i >> 2) & 63, s = (i >> 8) & 7;
        int r2 = i >> 11; int tap = r2 % 9, g = r2 / 9;
        int oc = g*32 + (lane & 31);
        int c  = s*16 + ((lane >> 5) << 3) + 2*j;
        float lo = dcn_w[(oc*128 + c)*9 + tap];
        float hi = dcn_w[(oc*128 + c + 1)*9 + tap];
        wpk[i] = f2bf(lo) | (f2bf(hi) << 16);
    }
    if (i < 9*8*256) {                     // off_w A-frags (27 oc, pad to 32)
        int j = i & 3, lane = (i >> 2) & 63, s = (i >> 8) & 7, tap = i >> 11;
        int oc = lane & 31;
        int c  = s*16 + ((lane >> 5) << 3) + 2*j;
        float lo = (oc < 27) ? off_w[(oc*128 + c)*9 + tap] : 0.f;
        float hi = (oc < 27) ? off_w[(oc*128 + c + 1)*9 + tap] : 0.f;
        wpo[i] = f2bf(lo) | (f2bf(hi) << 16);
    }
    if (i < 128) {
        float inv = g1[i] * rsqrtf(v1[i] + 1e-5f);
        bnw[i] = inv; bnw[128+i] = b1[i] - m1[i]*inv;
    } else if (i < 256) {
        int j = i - 128;
        float inv = g2[j] * rsqrtf(v2[j] + 1e-5f);
        bnw[256+j] = inv; bnw[384+j] = b2[j] - m2[j]*inv + inv*dcn_b[j];  // fold dcn bias
    } else if (i < 512) {
        int j = i - 256;
        float inv = g3[j] * rsqrtf(v3[j] + 1e-5f);
        bnw[512+j] = inv; bnw[768+j] = b3[j] - m3[j]*inv;
    }
}

// ---------------- k1: conv1x1 (256->128) + BN1 + SiLU -> Y2 bf16 NHWC ----------------
__global__ __launch_bounds__(256) void k1_cv1(
    const float* __restrict__ x, const float* __restrict__ w1,
    const float* __restrict__ bn, uint32_t* __restrict__ y2)
{
    __shared__ __align__(16) float Xs[16][64];
    __shared__ __align__(16) float Ws[16][132];
    int blk = blockIdx.x;
    int b = blk / 100, pix0 = (blk % 100) * 64;
    int t = threadIdx.x;
    int tx = t & 15, ty = t >> 4;                 // pix group / oc group
    float acc[8][4] = {};
    const float* xb = x + (size_t)b*CIN*HWX + pix0;

    for (int kk = 0; kk < 256; kk += 16) {
        {
            int kr = t >> 4, p4 = t & 15;
            *(float4*)&Xs[kr][p4*4] = *(const float4*)(xb + (kk + kr)*HWX + p4*4);
        }
        #pragma unroll
        for (int rep = 0; rep < 2; rep++) {
            int j = t + rep*256;
            int o = j >> 2, k4 = j & 3;
            float4 v = *(const float4*)(w1 + o*256 + kk + k4*4);
            Ws[k4*4+0][o] = v.x; Ws[k4*4+1][o] = v.y; Ws[k4*4+2][o] = v.z; Ws[k4*4+3][o] = v.w;
        }
        __syncthreads();
        #pragma unroll
        for (int kr = 0; kr < 16; kr++) {
            float4 xv = *(const float4*)&Xs[kr][tx*4];
            float4 wa = *(const float4*)&Ws[kr][ty*8];
            float4 wb = *(const float4*)&Ws[kr][ty*8+4];
            float w8[8] = {wa.x,wa.y,wa.z,wa.w,wb.x,wb.y,wb.z,wb.w};
            float xp[4] = {xv.x,xv.y,xv.z,xv.w};
            #pragma unroll
            for (int i = 0; i < 8; i++)
                #pragma unroll
                for (int j = 0; j < 4; j++) acc[i][j] += w8[i]*xp[j];
        }
        __syncthreads();
    }
    int o0 = ty*8;
    float vals[8][4];
    #pragma unroll
    for (int i = 0; i < 8; i++) {
        int o = o0 + i; float s = bn[o], be = bn[128+o];
        #pragma unroll
        for (int j = 0; j < 4; j++) vals[i][j] = silu_f(acc[i][j]*s + be);
    }
    uint32_t* y2b = y2 + (size_t)b*HWX*64;
    int pixb = pix0 + tx*4;
    #pragma unroll
    for (int j = 0; j < 4; j++) {
        uint32_t d0 = f2bf(vals[0][j]) | (f2bf(vals[1][j]) << 16);
        uint32_t d1 = f2bf(vals[2][j]) | (f2bf(vals[3][j]) << 16);
        uint32_t d2 = f2bf(vals[4][j]) | (f2bf(vals[5][j]) << 16);
        uint32_t d3 = f2bf(vals[6][j]) | (f2bf(vals[7][j]) << 16);
        uint4 q = make_uint4(d0, d1, d2, d3);
        *(uint4*)(y2b + (size_t)(pixb + j)*64 + ty*4) = q;
    }
}

// ---------------- k2: 3x3 conv (128->27, MFMA) + bias; mask sigmoided ----------------
// Implicit GEMM, no LDS: B-frags load straight from NHWC Y2 (lane pixel x 16B),
// A-frags from prepacked off_w (L1/L2-resident). 4 waves x 32 pixels each.
__global__ __launch_bounds__(256) void k2_off(
    const uint32_t* __restrict__ y2, const uint32_t* __restrict__ wpo,
    const float* __restrict__ ob, float* __restrict__ pred)
{
    int blk = blockIdx.x;                  // 8 * 50
    int b = blk / 50, pix0 = (blk % 50) * 128;
    int t = threadIdx.x;
    int lane = t & 63, w = t >> 6;
    int pixl = lane & 31, half = lane >> 5;
    int p = pix0 + w*32 + pixl;            // this lane's output pixel
    int h = p / WID, xw = p % WID;
    const uint32_t* yb = y2 + (size_t)b*HWX*64;
    floatx16 acc = {};

    for (int tap = 0; tap < 9; tap++) {
        int dy = tap/3 - 1, dx = tap%3 - 1;
        int gh = h + dy, gx = xw + dx;
        bool valid = (gh >= 0) && (gh < HGT) && (gx >= 0) && (gx < WID);
        const uint32_t* pp = yb + (size_t)(gh*WID + gx)*64 + half*4;
        const uint32_t* ap = wpo + (size_t)(tap*8)*256 + lane*4;
        #pragma unroll
        for (int s = 0; s < 8; s++) {
            U8 a, bf;
            const uint32_t* as = ap + s*256;
            a.u[0]=as[0]; a.u[1]=as[1]; a.u[2]=as[2]; a.u[3]=as[3];
            if (valid) {
                uint4 q = *(const uint4*)(pp + s*8);
                bf.u[0]=q.x; bf.u[1]=q.y; bf.u[2]=q.z; bf.u[3]=q.w;
            } else {
                bf.u[0]=0u; bf.u[1]=0u; bf.u[2]=0u; bf.u[3]=0u;
            }
            acc = __builtin_amdgcn_mfma_f32_32x32x16_bf16(a.s, bf.s, acc, 0, 0, 0);
        }
    }
    // epilogue: col=lane&31 (pix), row oc=(r&3)+8*(r>>2)+4*half
    float* pb = pred + (size_t)b*27*HWX;
    #pragma unroll
    for (int r = 0; r < 16; r++) {
        int oc = (r & 3) + 8*(r >> 2) + 4*half;
        if (oc < 27) {
            float v = acc[r] + ob[oc];
            if (oc >= 18) v = 1.f/(1.f+__expf(-v));   // pre-sigmoid mask
            pb[oc*HWX + p] = v;
        }
    }
}

// ---------------- k3: deformable conv (MFMA bf16) + BN2 + SiLU ----------------
// block: 4 waves, tile 128 oc x 32 pix. Per tap: coalesced NHWC gather ->
// S2[64 c2][33 pix] bf16x2 in LDS; per wave 8x mfma_f32_32x32x16_bf16 with
// A streamed prepacked from global (L2-resident).
#define S2S 33
__global__ __launch_bounds__(256) void k3_dcn(
    const uint32_t* __restrict__ y2, const float* __restrict__ pred,
    const uint32_t* __restrict__ wpk, const float* __restrict__ bn, float* __restrict__ z)
{
    __shared__ uint32_t S2[64*S2S];
    __shared__ int   sidx[32][4];
    __shared__ float swgt[32][4];
    int blk = blockIdx.x;                  // 1600
    int b = blk / 200, pix0 = (blk % 200) * 32;
    int t = threadIdx.x;
    int lane = t & 63, w = t >> 6;
    const float* pb = pred + (size_t)b*27*HWX;
    const uint32_t* yb = y2 + (size_t)b*HWX*64;
    floatx16 acc = {};

    for (int tap = 0; tap < 9; tap++) {
        __syncthreads();                   // prev tap's GEMM done
        if (t < 32) {                      // per-pixel bilinear params
            int pix = pix0 + t;
            int h = pix / WID, wq = pix % WID;
            float dy = pb[(2*tap)*HWX + pix];
            float dx = pb[(2*tap+1)*HWX + pix];
            float mk = pb[(18+tap)*HWX + pix];
            float pyf = (float)(h - 1 + tap/3) + dy;
            float pxf = (float)(wq - 1 + tap%3) + dx;
            float y0f = floorf(pyf), x0f = floorf(pxf);
            float wy1 = pyf - y0f, wx1 = pxf - x0f;
            int iy0 = (int)y0f, ix0 = (int)x0f;
            int iy1 = iy0 + 1,  ix1 = ix0 + 1;
            float vy0 = (iy0 >= 0 && iy0 < HGT) ? 1.f : 0.f;
            float vy1 = (iy1 >= 0 && iy1 < HGT) ? 1.f : 0.f;
            float vx0 = (ix0 >= 0 && ix0 < WID) ? 1.f : 0.f;
            float vx1 = (ix1 >= 0 && ix1 < WID) ? 1.f : 0.f;
            int cy0 = min(max(iy0,0),HGT-1), cy1 = min(max(iy1,0),HGT-1);
            int cx0 = min(max(ix0,0),WID-1), cx1 = min(max(ix1,0),WID-1);
            sidx[t][0] = cy0*WID+cx0; sidx[t][1] = cy0*WID+cx1;
            sidx[t][2] = cy1*WID+cx0; sidx[t][3] = cy1*WID+cx1;
            swgt[t][0] = (1.f-wy1)*(1.f-wx1)*mk*vy0*vx0;
            swgt[t][1] = (1.f-wy1)*wx1*mk*vy0*vx1;
            swgt[t][2] = wy1*(1.f-wx1)*mk*vy1*vx0;
            swgt[t][3] = wy1*wx1*mk*vy1*vx1;
        }
        __syncthreads();
        // build S2: per pass, whole wave = one pixel, lane = c2 (coalesced 256B/corner)
        #pragma unroll
        for (int p = 0; p < 8; p++) {
            int pix = p*4 + w;
            int i0 = sidx[pix][0], i1 = sidx[pix][1], i2 = sidx[pix][2], i3 = sidx[pix][3];
            float w0 = swgt[pix][0], w1 = swgt[pix][1], w2 = swgt[pix][2], w3 = swgt[pix][3];
            uint32_t u0 = yb[i0*64 + lane], u1 = yb[i1*64 + lane];
            uint32_t u2 = yb[i2*64 + lane], u3 = yb[i3*64 + lane];
            float lo = w0*bf16lo(u0) + w1*bf16lo(u1) + w2*bf16lo(u2) + w3*bf16lo(u3);
            float hi = w0*bf16hi(u0) + w1*bf16hi(u1) + w2*bf16hi(u2) + w3*bf16hi(u3);
            S2[lane*S2S + pix] = f2bf(lo) | (f2bf(hi) << 16);
        }
        __syncthreads();
        // GEMM for this tap: 8 K-steps of 32x32x16
        const uint32_t* wp = wpk + (size_t)((w*9 + tap)*8)*256 + lane*4;
        int kb = (lane >> 5) * 4;          // c2 sub-offset
        int pixl = lane & 31;
        #pragma unroll
        for (int s = 0; s < 8; s++) {
            U8 a, bf;
            const uint32_t* wps = wp + s*256;
            a.u[0] = wps[0]; a.u[1] = wps[1]; a.u[2] = wps[2]; a.u[3] = wps[3];
            int c2b = s*8 + kb;
            bf.u[0] = S2[(c2b+0)*S2S + pixl];
            bf.u[1] = S2[(c2b+1)*S2S + pixl];
            bf.u[2] = S2[(c2b+2)*S2S + pixl];
            bf.u[3] = S2[(c2b+3)*S2S + pixl];
            acc = __builtin_amdgcn_mfma_f32_32x32x16_bf16(a.s, bf.s, acc, 0, 0, 0);
        }
    }
    // epilogue: D layout col=lane&31 (pix), row=(r&3)+8*(r>>2)+4*(lane>>5)
    int pixg = pix0 + (lane & 31);
    float* zb = z + (size_t)b*CMID*HWX + pixg;
    #pragma unroll
    for (int r = 0; r < 16; r++) {
        int oc = w*32 + (r & 3) + 8*(r >> 2) + 4*(lane >> 5);
        float sc = bn[256+oc], be = bn[384+oc];
        zb[oc*HWX] = silu_f(acc[r]*sc + be);
    }
}

// ---------------- k4: conv1x1 (128->256) + BN3 + SiLU + residual ----------------
__global__ __launch_bounds__(256) void k4_cv3(
    const float* __restrict__ z, const float* __restrict__ w3,
    const float* __restrict__ bn, const float* __restrict__ x, float* __restrict__ out)
{
    __shared__ __align__(16) float Zs[16][64];
    __shared__ __align__(16) float Ws[16][132];
    int blk = blockIdx.x;                  // 8*100*2
    int half = blk & 1, blk2 = blk >> 1;
    int b = blk2 / 100, pix0 = (blk2 % 100) * 64;
    int t = threadIdx.x;
    int tx = t & 15, ty = t >> 4;
    float acc[8][4] = {};
    const float* zb = z + (size_t)b*CMID*HWX + pix0;
    const float* w3h = w3 + half*128*CMID;

    for (int kk = 0; kk < 128; kk += 16) {
        {
            int kr = t >> 4, p4 = t & 15;
            *(float4*)&Zs[kr][p4*4] = *(const float4*)(zb + (kk + kr)*HWX + p4*4);
        }
        #pragma unroll
        for (int rep = 0; rep < 2; rep++) {
            int j = t + rep*256;
            int o = j >> 2, k4 = j & 3;
            float4 v = *(const float4*)(w3h + o*CMID + kk + k4*4);
            Ws[k4*4+0][o] = v.x; Ws[k4*4+1][o] = v.y; Ws[k4*4+2][o] = v.z; Ws[k4*4+3][o] = v.w;
        }
        __syncthreads();
        #pragma unroll
        for (int kr = 0; kr < 16; kr++) {
            float4 xv = *(const float4*)&Zs[kr][tx*4];
            float4 wa = *(const float4*)&Ws[kr][ty*8];
            float4 wb = *(const float4*)&Ws[kr][ty*8+4];
            float w8[8] = {wa.x,wa.y,wa.z,wa.w,wb.x,wb.y,wb.z,wb.w};
            float xp[4] = {xv.x,xv.y,xv.z,xv.w};
            #pragma unroll
            for (int i = 0; i < 8; i++)
                #pragma unroll
                for (int j = 0; j < 4; j++) acc[i][j] += w8[i]*xp[j];
        }
        __syncthreads();
    }
    int o0 = ty*8;
    const float* xb = x + (size_t)b*COUT*HWX + (size_t)half*128*HWX + pix0 + tx*4;
    float* ob = out + (size_t)b*COUT*HWX + (size_t)half*128*HWX + pix0 + tx*4;
    #pragma unroll
    for (int i = 0; i < 8; i++) {
        int og = half*128 + o0 + i;
        float s = bn[512+og], be = bn[768+og];
        float4 xr = *(const float4*)(xb + (o0+i)*HWX);
        float4 r;
        r.x = xr.x + silu_f(acc[i][0]*s+be); r.y = xr.y + silu_f(acc[i][1]*s+be);
        r.z = xr.z + silu_f(acc[i][2]*s+be); r.w = xr.w + silu_f(acc[i][3]*s+be);
        *(float4*)(ob + (o0+i)*HWX) = r;
    }
}

extern "C" void kernel_launch(void* const* d_in, const int* in_sizes, int n_in,
                              void* d_out, int out_size, void* d_ws, size_t ws_size,
                              hipStream_t stream) {
    const float* x     = (const float*)d_in[0];
    const float* cv1_w = (const float*)d_in[1];
    const float* bn1_g = (const float*)d_in[2];
    const float* bn1_b = (const float*)d_in[3];
    const float* bn1_m = (const float*)d_in[4];
    const float* bn1_v = (const float*)d_in[5];
    const float* off_w = (const float*)d_in[6];
    const float* off_b = (const float*)d_in[7];
    const float* dcn_w = (const float*)d_in[8];
    const float* dcn_b = (const float*)d_in[9];
    const float* bn2_g = (const float*)d_in[10];
    const float* bn2_b = (const float*)d_in[11];
    const float* bn2_m = (const float*)d_in[12];
    const float* bn2_v = (const float*)d_in[13];
    const float* cv3_w = (const float*)d_in[14];
    const float* bn3_g = (const float*)d_in[15];
    const float* bn3_b = (const float*)d_in[16];
    const float* bn3_m = (const float*)d_in[17];
    const float* bn3_v = (const float*)d_in[18];

    float* ws   = (float*)d_ws;
    float*    PRED = ws + WS_PRED;
    float*    Z    = ws + WS_Z;
    float*    BN   = ws + WS_BN;
    uint32_t* Y2   = (uint32_t*)(ws + WS_Y2);
    uint32_t* WPK  = (uint32_t*)(ws + WS_WPK);
    uint32_t* WPO  = (uint32_t*)(ws + WS_WPO);

    hipLaunchKernelGGL(k0_prep, dim3(288), dim3(256), 0, stream,
        dcn_w, off_w, bn1_g, bn1_b, bn1_m, bn1_v,
        bn2_g, bn2_b, bn2_m, bn2_v, dcn_b,
        bn3_g, bn3_b, bn3_m, bn3_v, WPK, WPO, BN);
    hipLaunchKernelGGL(k1_cv1, dim3(800), dim3(256), 0, stream, x, cv1_w, BN, Y2);
    hipLaunchKernelGGL(k2_off, dim3(400), dim3(256), 0, stream, Y2, WPO, off_b, PRED);
    hipLaunchKernelGGL(k3_dcn, dim3(1600), dim3(256), 0, stream, Y2, PRED, WPK, BN, Z);
    hipLaunchKernelGGL(k4_cv3, dim3(1600), dim3(256), 0, stream, Z, cv3_w, BN, x, (float*)d_out);
}

// Round 4
// 247.506 us; speedup vs baseline: 3.8396x; 1.2795x over previous
//
#include <hip/hip_runtime.h>
#include <math.h>

// Problem constants
#define HWX   6400   // 80*80
#define WID   80
#define HGT   80
#define CMID  128
#define CIN   256
#define COUT  256

// Workspace layout (float/dword offsets)
#define WS_PRED 0            // (8,27,80,80) fp32 = 1,382,400
#define WS_BN   1382400      // s1[128] b1[128] s2[128] b2[128] s3[256] b3[256] = 1024
#define WS_Y2   1383424      // (8,6400,128) bf16 NHWC = 3,276,800 dwords
#define WS_Z2   4660224      // (8,6400,128) bf16 NHWC = 3,276,800 dwords
#define WS_WPK  7937024      // dcn_w prepacked A-frags: 73,728 dwords
#define WS_WPO  8010752      // off_w prepacked A-frags: 18,432 dwords
#define WS_WP1  8029184      // cv1_w prepacked A-frags: 16,384 dwords
#define WS_WP3  8045568      // cv3_w prepacked A-frags: 16,384 dwords

typedef float floatx16 __attribute__((ext_vector_type(16)));
typedef short shortx8  __attribute__((ext_vector_type(8)));

union U8 { uint32_t u[4]; shortx8 s; };

__device__ __forceinline__ float silu_f(float t){ return t / (1.f + __expf(-t)); }
__device__ __forceinline__ float bf16lo(uint32_t u){ return __uint_as_float(u << 16); }
__device__ __forceinline__ float bf16hi(uint32_t u){ return __uint_as_float(u & 0xffff0000u); }
__device__ __forceinline__ uint32_t f2bf(float f){           // RNE fp32->bf16
    uint32_t u = __float_as_uint(f);
    return (u + 0x7fffu + ((u >> 16) & 1u)) >> 16;
}

// ---------------- prep: BN fold + MFMA weight prepacks ----------------
// A-frag convention (verified in k2/k3): lane's oc = g*32 + (lane&31);
// k-index c = s*16 + (lane>>5)*8 + 2j (+1 in hi half of dword j).
__global__ __launch_bounds__(256) void k0_prep(
    const float* __restrict__ dcn_w, const float* __restrict__ off_w,
    const float* __restrict__ cv1_w, const float* __restrict__ cv3_w,
    const float* __restrict__ g1, const float* __restrict__ b1, const float* __restrict__ m1, const float* __restrict__ v1,
    const float* __restrict__ g2, const float* __restrict__ b2, const float* __restrict__ m2, const float* __restrict__ v2,
    const float* __restrict__ dcn_b,
    const float* __restrict__ g3, const float* __restrict__ b3, const float* __restrict__ m3, const float* __restrict__ v3,
    uint32_t* __restrict__ wpk, uint32_t* __restrict__ wpo,
    uint32_t* __restrict__ wp1, uint32_t* __restrict__ wp3, float* __restrict__ bnw)
{
    int i = blockIdx.x * 256 + threadIdx.x;
    if (i < 4*9*8*256) {                   // dcn_w: ((g*9+tap)*8+s)*256 + lane*4 + j
        int j = i & 3, lane = (i >> 2) & 63, s = (i >> 8) & 7;
        int r2 = i >> 11; int tap = r2 % 9, g = r2 / 9;
        int oc = g*32 + (lane & 31);
        int c  = s*16 + ((lane >> 5) << 3) + 2*j;
        wpk[i] = f2bf(dcn_w[(oc*128 + c)*9 + tap]) | (f2bf(dcn_w[(oc*128 + c + 1)*9 + tap]) << 16);
    }
    if (i < 9*8*256) {                     // off_w (27 oc pad 32): (tap*8+s)*256 + lane*4 + j
        int j = i & 3, lane = (i >> 2) & 63, s = (i >> 8) & 7, tap = i >> 11;
        int oc = lane & 31;
        int c  = s*16 + ((lane >> 5) << 3) + 2*j;
        float lo = (oc < 27) ? off_w[(oc*128 + c)*9 + tap] : 0.f;
        float hi = (oc < 27) ? off_w[(oc*128 + c + 1)*9 + tap] : 0.f;
        wpo[i] = f2bf(lo) | (f2bf(hi) << 16);
    }
    if (i < 4*16*256) {                    // cv1_w (128x256): (g*16+s)*256 + lane*4 + j
        int j = i & 3, lane = (i >> 2) & 63, s = (i >> 8) & 15, g = i >> 12;
        int oc = g*32 + (lane & 31);
        int c  = s*16 + ((lane >> 5) << 3) + 2*j;
        wp1[i] = f2bf(cv1_w[oc*256 + c]) | (f2bf(cv1_w[oc*256 + c + 1]) << 16);
    }
    if (i < 8*8*256) {                     // cv3_w (256x128): (g*8+s)*256 + lane*4 + j
        int j = i & 3, lane = (i >> 2) & 63, s = (i >> 8) & 7, g = i >> 11;
        int oc = g*32 + (lane & 31);
        int c  = s*16 + ((lane >> 5) << 3) + 2*j;
        wp3[i] = f2bf(cv3_w[oc*128 + c]) | (f2bf(cv3_w[oc*128 + c + 1]) << 16);
    }
    if (i < 128) {
        float inv = g1[i] * rsqrtf(v1[i] + 1e-5f);
        bnw[i] = inv; bnw[128+i] = b1[i] - m1[i]*inv;
    } else if (i < 256) {
        int j = i - 128;
        float inv = g2[j] * rsqrtf(v2[j] + 1e-5f);
        bnw[256+j] = inv; bnw[384+j] = b2[j] - m2[j]*inv + inv*dcn_b[j];  // fold dcn bias
    } else if (i < 512) {
        int j = i - 256;
        float inv = g3[j] * rsqrtf(v3[j] + 1e-5f);
        bnw[512+j] = inv; bnw[768+j] = b3[j] - m3[j]*inv;
    }
}

// ---------------- k1: conv1x1 (256->128, MFMA) + BN1 + SiLU -> Y2 bf16 NHWC ----------------
// 4 waves; tile 128 oc x 64 pix; wave w = oc group; K staged 32-ch chunks via LDS.
#define K1PAD 68
__global__ __launch_bounds__(256) void k1_cv1(
    const float* __restrict__ x, const uint32_t* __restrict__ wp1,
    const float* __restrict__ bn, uint32_t* __restrict__ y2)
{
    __shared__ uint32_t L[64*66];          // staging uses [0..16*68); epilogue transpose [64][66]
    int blk = blockIdx.x;                  // 800
    int b = blk / 100, pix0 = (blk % 100) * 64;
    int t = threadIdx.x;
    int lane = t & 63, w = t >> 6;
    int pixl = lane & 31, bhalf = lane >> 5;
    floatx16 acc0 = {}, acc1 = {};
    const float* xb = x + (size_t)b*CIN*HWX + pix0;
    const uint32_t* wpg = wp1 + (size_t)(w*16)*256 + lane*4;

    int r2 = t >> 4, c4 = (t & 15) * 4;    // staging: thread loads ch pair (2*r2,2*r2+1), 4 pix
    for (int kk = 0; kk < 256; kk += 32) {
        float4 a0 = *(const float4*)(xb + (size_t)(kk + 2*r2)*HWX + c4);
        float4 a1 = *(const float4*)(xb + (size_t)(kk + 2*r2 + 1)*HWX + c4);
        uint4 q;
        q.x = f2bf(a0.x) | (f2bf(a1.x) << 16);
        q.y = f2bf(a0.y) | (f2bf(a1.y) << 16);
        q.z = f2bf(a0.z) | (f2bf(a1.z) << 16);
        q.w = f2bf(a0.w) | (f2bf(a1.w) << 16);
        __syncthreads();                   // prev iter's frag reads done
        *(uint4*)&L[r2*K1PAD + c4] = q;
        __syncthreads();
        #pragma unroll
        for (int sl = 0; sl < 2; sl++) {
            int s = (kk >> 4) + sl;
            U8 a, b0, b1;
            const uint32_t* as = wpg + s*256;
            a.u[0]=as[0]; a.u[1]=as[1]; a.u[2]=as[2]; a.u[3]=as[3];
            int row = sl*8 + bhalf*4;
            #pragma unroll
            for (int j = 0; j < 4; j++) b0.u[j] = L[(row+j)*K1PAD + pixl];
            #pragma unroll
            for (int j = 0; j < 4; j++) b1.u[j] = L[(row+j)*K1PAD + 32 + pixl];
            acc0 = __builtin_amdgcn_mfma_f32_32x32x16_bf16(a.s, b0.s, acc0, 0, 0, 0);
            acc1 = __builtin_amdgcn_mfma_f32_32x32x16_bf16(a.s, b1.s, acc1, 0, 0, 0);
        }
    }
    __syncthreads();
    // epilogue: BN+SiLU, pack oc pairs, LDS transpose to [pix][c2]
    #pragma unroll
    for (int r = 0; r < 16; r += 2) {
        int oc = w*32 + (r & 3) + 8*(r >> 2) + 4*bhalf;      // even; pair (oc, oc+1)
        float s0 = bn[oc],   be0 = bn[128+oc];
        float s1 = bn[oc+1], be1 = bn[128+oc+1];
        uint32_t d0 = f2bf(silu_f(acc0[r]*s0+be0)) | (f2bf(silu_f(acc0[r+1]*s1+be1)) << 16);
        uint32_t d1 = f2bf(silu_f(acc1[r]*s0+be0)) | (f2bf(silu_f(acc1[r+1]*s1+be1)) << 16);
        int oc2 = oc >> 1;
        L[pixl*66 + oc2]        = d0;
        L[(32+pixl)*66 + oc2]   = d1;
    }
    __syncthreads();
    uint32_t* y2b = y2 + (size_t)b*HWX*64 + (size_t)pix0*64;
    int q2 = t & 31, p0 = t >> 5;
    #pragma unroll
    for (int pp = 0; pp < 8; pp++) {
        int pix = p0 + pp*8;
        uint2 v = make_uint2(L[pix*66 + q2*2], L[pix*66 + q2*2 + 1]);
        *(uint2*)(y2b + (size_t)pix*64 + q2*2) = v;
    }
}

// ---------------- k2: 3x3 conv (128->27, MFMA) + bias; mask sigmoided ----------------
__global__ __launch_bounds__(256) void k2_off(
    const uint32_t* __restrict__ y2, const uint32_t* __restrict__ wpo,
    const float* __restrict__ ob, float* __restrict__ pred)
{
    int blk = blockIdx.x;                  // 8 * 50
    int b = blk / 50, pix0 = (blk % 50) * 128;
    int t = threadIdx.x;
    int lane = t & 63, w = t >> 6;
    int pixl = lane & 31, half = lane >> 5;
    int p = pix0 + w*32 + pixl;
    int h = p / WID, xw = p % WID;
    const uint32_t* yb = y2 + (size_t)b*HWX*64;
    floatx16 acc = {};

    for (int tap = 0; tap < 9; tap++) {
        int dy = tap/3 - 1, dx = tap%3 - 1;
        int gh = h + dy, gx = xw + dx;
        bool valid = (gh >= 0) && (gh < HGT) && (gx >= 0) && (gx < WID);
        const uint32_t* pp = yb + (size_t)(gh*WID + gx)*64 + half*4;
        const uint32_t* ap = wpo + (size_t)(tap*8)*256 + lane*4;
        #pragma unroll
        for (int s = 0; s < 8; s++) {
            U8 a, bf;
            const uint32_t* as = ap + s*256;
            a.u[0]=as[0]; a.u[1]=as[1]; a.u[2]=as[2]; a.u[3]=as[3];
            if (valid) {
                uint4 q = *(const uint4*)(pp + s*8);
                bf.u[0]=q.x; bf.u[1]=q.y; bf.u[2]=q.z; bf.u[3]=q.w;
            } else {
                bf.u[0]=0u; bf.u[1]=0u; bf.u[2]=0u; bf.u[3]=0u;
            }
            acc = __builtin_amdgcn_mfma_f32_32x32x16_bf16(a.s, bf.s, acc, 0, 0, 0);
        }
    }
    float* pb = pred + (size_t)b*27*HWX;
    #pragma unroll
    for (int r = 0; r < 16; r++) {
        int oc = (r & 3) + 8*(r >> 2) + 4*half;
        if (oc < 27) {
            float v = acc[r] + ob[oc];
            if (oc >= 18) v = 1.f/(1.f+__expf(-v));
            pb[oc*HWX + p] = v;
        }
    }
}

// ---------------- k3: deformable conv (MFMA bf16) + BN2 + SiLU -> Z2 bf16 NHWC ----------------
#define S2S 33
__global__ __launch_bounds__(256) void k3_dcn(
    const uint32_t* __restrict__ y2, const float* __restrict__ pred,
    const uint32_t* __restrict__ wpk, const float* __restrict__ bn, uint32_t* __restrict__ z2)
{
    __shared__ uint32_t S2[64*S2S];        // 2112 dwords; epilogue reuses as [32][66]
    __shared__ int   sidx[32][4];
    __shared__ float swgt[32][4];
    int blk = blockIdx.x;                  // 1600
    int b = blk / 200, pix0 = (blk % 200) * 32;
    int t = threadIdx.x;
    int lane = t & 63, w = t >> 6;
    int pixl = lane & 31, bhalf = lane >> 5;
    const float* pb = pred + (size_t)b*27*HWX;
    const uint32_t* yb = y2 + (size_t)b*HWX*64;
    floatx16 acc = {};

    for (int tap = 0; tap < 9; tap++) {
        __syncthreads();
        if (t < 32) {
            int pix = pix0 + t;
            int h = pix / WID, wq = pix % WID;
            float dy = pb[(2*tap)*HWX + pix];
            float dx = pb[(2*tap+1)*HWX + pix];
            float mk = pb[(18+tap)*HWX + pix];
            float pyf = (float)(h - 1 + tap/3) + dy;
            float pxf = (float)(wq - 1 + tap%3) + dx;
            float y0f = floorf(pyf), x0f = floorf(pxf);
            float wy1 = pyf - y0f, wx1 = pxf - x0f;
            int iy0 = (int)y0f, ix0 = (int)x0f;
            int iy1 = iy0 + 1,  ix1 = ix0 + 1;
            float vy0 = (iy0 >= 0 && iy0 < HGT) ? 1.f : 0.f;
            float vy1 = (iy1 >= 0 && iy1 < HGT) ? 1.f : 0.f;
            float vx0 = (ix0 >= 0 && ix0 < WID) ? 1.f : 0.f;
            float vx1 = (ix1 >= 0 && ix1 < WID) ? 1.f : 0.f;
            int cy0 = min(max(iy0,0),HGT-1), cy1 = min(max(iy1,0),HGT-1);
            int cx0 = min(max(ix0,0),WID-1), cx1 = min(max(ix1,0),WID-1);
            sidx[t][0] = cy0*WID+cx0; sidx[t][1] = cy0*WID+cx1;
            sidx[t][2] = cy1*WID+cx0; sidx[t][3] = cy1*WID+cx1;
            swgt[t][0] = (1.f-wy1)*(1.f-wx1)*mk*vy0*vx0;
            swgt[t][1] = (1.f-wy1)*wx1*mk*vy0*vx1;
            swgt[t][2] = wy1*(1.f-wx1)*mk*vy1*vx0;
            swgt[t][3] = wy1*wx1*mk*vy1*vx1;
        }
        __syncthreads();
        #pragma unroll
        for (int p = 0; p < 8; p++) {
            int pix = p*4 + w;
            int i0 = sidx[pix][0], i1 = sidx[pix][1], i2 = sidx[pix][2], i3 = sidx[pix][3];
            float w0 = swgt[pix][0], w1 = swgt[pix][1], w2 = swgt[pix][2], w3 = swgt[pix][3];
            uint32_t u0 = yb[i0*64 + lane], u1 = yb[i1*64 + lane];
            uint32_t u2 = yb[i2*64 + lane], u3 = yb[i3*64 + lane];
            float lo = w0*bf16lo(u0) + w1*bf16lo(u1) + w2*bf16lo(u2) + w3*bf16lo(u3);
            float hi = w0*bf16hi(u0) + w1*bf16hi(u1) + w2*bf16hi(u2) + w3*bf16hi(u3);
            S2[lane*S2S + pix] = f2bf(lo) | (f2bf(hi) << 16);
        }
        __syncthreads();
        const uint32_t* wp = wpk + (size_t)((w*9 + tap)*8)*256 + lane*4;
        int kb = bhalf * 4;
        #pragma unroll
        for (int s = 0; s < 8; s++) {
            U8 a, bf;
            const uint32_t* wps = wp + s*256;
            a.u[0] = wps[0]; a.u[1] = wps[1]; a.u[2] = wps[2]; a.u[3] = wps[3];
            int c2b = s*8 + kb;
            bf.u[0] = S2[(c2b+0)*S2S + pixl];
            bf.u[1] = S2[(c2b+1)*S2S + pixl];
            bf.u[2] = S2[(c2b+2)*S2S + pixl];
            bf.u[3] = S2[(c2b+3)*S2S + pixl];
            acc = __builtin_amdgcn_mfma_f32_32x32x16_bf16(a.s, bf.s, acc, 0, 0, 0);
        }
    }
    __syncthreads();                       // last tap's S2 reads done
    // epilogue: BN2+SiLU, pack oc pairs, transpose via LDS, write Z2 NHWC
    #pragma unroll
    for (int r = 0; r < 16; r += 2) {
        int oc = w*32 + (r & 3) + 8*(r >> 2) + 4*bhalf;
        float s0 = bn[256+oc],   be0 = bn[384+oc];
        float s1 = bn[256+oc+1], be1 = bn[384+oc+1];
        uint32_t d = f2bf(silu_f(acc[r]*s0+be0)) | (f2bf(silu_f(acc[r+1]*s1+be1)) << 16);
        S2[pixl*66 + (oc >> 1)] = d;
    }
    __syncthreads();
    uint32_t* z2b = z2 + (size_t)b*HWX*64 + (size_t)pix0*64;
    int q2 = t & 31, p0 = t >> 5;
    #pragma unroll
    for (int pp = 0; pp < 4; pp++) {
        int pix = p0 + pp*8;
        uint2 v = make_uint2(S2[pix*66 + q2*2], S2[pix*66 + q2*2 + 1]);
        *(uint2*)(z2b + (size_t)pix*64 + q2*2) = v;
    }
}

// ---------------- k4: conv1x1 (128->256, MFMA) + BN3 + SiLU + residual ----------------
// Zero-LDS implicit GEMM: B-frags straight from Z2 NHWC.
__global__ __launch_bounds__(256) void k4_cv3(
    const uint32_t* __restrict__ z2, const uint32_t* __restrict__ wp3,
    const float* __restrict__ bn, const float* __restrict__ x, float* __restrict__ out)
{
    int blk = blockIdx.x;                  // 1600
    int half = blk & 1, blk2 = blk >> 1;
    int b = blk2 / 100, pix0 = (blk2 % 100) * 64;
    int t = threadIdx.x;
    int lane = t & 63, w = t >> 6;
    int pixl = lane & 31, bhalf = lane >> 5;
    int g = half*4 + w;
    floatx16 acc0 = {}, acc1 = {};
    const uint32_t* zb = z2 + (size_t)b*HWX*64 + (size_t)pix0*64;
    const uint32_t* wpg = wp3 + (size_t)(g*8)*256 + lane*4;

    #pragma unroll
    for (int s = 0; s < 8; s++) {
        U8 a, b0, b1;
        const uint32_t* as = wpg + s*256;
        a.u[0]=as[0]; a.u[1]=as[1]; a.u[2]=as[2]; a.u[3]=as[3];
        uint4 q0 = *(const uint4*)(zb + (size_t)pixl*64 + s*8 + bhalf*4);
        uint4 q1 = *(const uint4*)(zb + (size_t)(32+pixl)*64 + s*8 + bhalf*4);
        b0.u[0]=q0.x; b0.u[1]=q0.y; b0.u[2]=q0.z; b0.u[3]=q0.w;
        b1.u[0]=q1.x; b1.u[1]=q1.y; b1.u[2]=q1.z; b1.u[3]=q1.w;
        acc0 = __builtin_amdgcn_mfma_f32_32x32x16_bf16(a.s, b0.s, acc0, 0, 0, 0);
        acc1 = __builtin_amdgcn_mfma_f32_32x32x16_bf16(a.s, b1.s, acc1, 0, 0, 0);
    }
    const float* xb = x + (size_t)b*COUT*HWX + pix0;
    float* ob = out + (size_t)b*COUT*HWX + pix0;
    #pragma unroll
    for (int r = 0; r < 16; r++) {
        int oc = g*32 + (r & 3) + 8*(r >> 2) + 4*bhalf;
        float sc = bn[512+oc], be = bn[768+oc];
        float v0 = silu_f(acc0[r]*sc+be) + xb[(size_t)oc*HWX + pixl];
        float v1 = silu_f(acc1[r]*sc+be) + xb[(size_t)oc*HWX + 32 + pixl];
        ob[(size_t)oc*HWX + pixl]      = v0;
        ob[(size_t)oc*HWX + 32 + pixl] = v1;
    }
}

extern "C" void kernel_launch(void* const* d_in, const int* in_sizes, int n_in,
                              void* d_out, int out_size, void* d_ws, size_t ws_size,
                              hipStream_t stream) {
    const float* x     = (const float*)d_in[0];
    const float* cv1_w = (const float*)d_in[1];
    const float* bn1_g = (const float*)d_in[2];
    const float* bn1_b = (const float*)d_in[3];
    const float* bn1_m = (const float*)d_in[4];
    const float* bn1_v = (const float*)d_in[5];
    const float* off_w = (const float*)d_in[6];
    const float* off_b = (const float*)d_in[7];
    const float* dcn_w = (const float*)d_in[8];
    const float* dcn_b = (const float*)d_in[9];
    const float* bn2_g = (const float*)d_in[10];
    const float* bn2_b = (const float*)d_in[11];
    const float* bn2_m = (const float*)d_in[12];
    const float* bn2_v = (const float*)d_in[13];
    const float* cv3_w = (const float*)d_in[14];
    const float* bn3_g = (const float*)d_in[15];
    const float* bn3_b = (const float*)d_in[16];
    const float* bn3_m = (const float*)d_in[17];
    const float* bn3_v = (const float*)d_in[18];

    float* ws   = (float*)d_ws;
    float*    PRED = ws + WS_PRED;
    float*    BN   = ws + WS_BN;
    uint32_t* Y2   = (uint32_t*)(ws + WS_Y2);
    uint32_t* Z2   = (uint32_t*)(ws + WS_Z2);
    uint32_t* WPK  = (uint32_t*)(ws + WS_WPK);
    uint32_t* WPO  = (uint32_t*)(ws + WS_WPO);
    uint32_t* WP1  = (uint32_t*)(ws + WS_WP1);
    uint32_t* WP3  = (uint32_t*)(ws + WS_WP3);

    hipLaunchKernelGGL(k0_prep, dim3(288), dim3(256), 0, stream,
        dcn_w, off_w, cv1_w, cv3_w,
        bn1_g, bn1_b, bn1_m, bn1_v,
        bn2_g, bn2_b, bn2_m, bn2_v, dcn_b,
        bn3_g, bn3_b, bn3_m, bn3_v, WPK, WPO, WP1, WP3, BN);
    hipLaunchKernelGGL(k1_cv1, dim3(800), dim3(256), 0, stream, x, WP1, BN, Y2);
    hipLaunchKernelGGL(k2_off, dim3(400), dim3(256), 0, stream, Y2, WPO, off_b, PRED);
    hipLaunchKernelGGL(k3_dcn, dim3(1600), dim3(256), 0, stream, Y2, PRED, WPK, BN, Z2);
    hipLaunchKernelGGL(k4_cv3, dim3(1600), dim3(256), 0, stream, Z2, WP3, BN, x, (float*)d_out);
}

// Round 5
// 244.164 us; speedup vs baseline: 3.8922x; 1.0137x over previous
//
#include <hip/hip_runtime.h>
#include <math.h>

// Problem constants
#define HWX   6400   // 80*80
#define WID   80
#define HGT   80
#define CMID  128
#define CIN   256
#define COUT  256

// Workspace layout (float/dword offsets)
#define WS_PRED 0            // (8,27,80,80) fp32 = 1,382,400
#define WS_BN   1382400      // s1[128] b1[128] s2[128] b2[128] s3[256] b3[256] = 1024
#define WS_Y2   1383424      // (8,6400,128) bf16 NHWC = 3,276,800 dwords
#define WS_Z2   4660224      // (8,6400,128) bf16 NHWC = 3,276,800 dwords
#define WS_WPK  7937024      // dcn_w prepacked A-frags: 73,728 dwords
#define WS_WPO  8010752      // off_w prepacked A-frags: 18,432 dwords
#define WS_WP1  8029184      // cv1_w prepacked A-frags: 16,384 dwords
#define WS_WP3  8045568      // cv3_w prepacked A-frags: 16,384 dwords

typedef float floatx16 __attribute__((ext_vector_type(16)));
typedef short shortx8  __attribute__((ext_vector_type(8)));
typedef float floatx2  __attribute__((ext_vector_type(2)));

union U8 { uint32_t u[4]; shortx8 s; };

__device__ __forceinline__ float silu_f(float t){ return t / (1.f + __expf(-t)); }
__device__ __forceinline__ float bf16lo(uint32_t u){ return __uint_as_float(u << 16); }
__device__ __forceinline__ float bf16hi(uint32_t u){ return __uint_as_float(u & 0xffff0000u); }
__device__ __forceinline__ uint32_t f2bf(float f){           // RNE fp32->bf16 (cold paths)
    uint32_t u = __float_as_uint(f);
    return (u + 0x7fffu + ((u >> 16) & 1u)) >> 16;
}
// unpack bf16x2 dword -> float2 (lo, hi)
__device__ __forceinline__ floatx2 up2(uint32_t u){
    floatx2 r; r.x = __uint_as_float(u << 16); r.y = __uint_as_float(u & 0xffff0000u); return r;
}
// pack float2 -> bf16x2 dword (round-half-up: +0x8000 then take high halves via v_perm)
__device__ __forceinline__ uint32_t pk2(floatx2 v){
    return __builtin_amdgcn_perm(__float_as_uint(v.y) + 0x8000u,
                                 __float_as_uint(v.x) + 0x8000u, 0x07060302u);
}
__device__ __forceinline__ uint32_t pk2f(float a, float b){ floatx2 v; v.x=a; v.y=b; return pk2(v); }

// ---------------- prep: BN fold + MFMA weight prepacks ----------------
// A-frag convention (verified): lane's oc = g*32 + (lane&31);
// k-index c = s*16 + (lane>>5)*8 + 2j (+1 in hi half of dword j).
__global__ __launch_bounds__(256) void k0_prep(
    const float* __restrict__ dcn_w, const float* __restrict__ off_w,
    const float* __restrict__ cv1_w, const float* __restrict__ cv3_w,
    const float* __restrict__ g1, const float* __restrict__ b1, const float* __restrict__ m1, const float* __restrict__ v1,
    const float* __restrict__ g2, const float* __restrict__ b2, const float* __restrict__ m2, const float* __restrict__ v2,
    const float* __restrict__ dcn_b,
    const float* __restrict__ g3, const float* __restrict__ b3, const float* __restrict__ m3, const float* __restrict__ v3,
    uint32_t* __restrict__ wpk, uint32_t* __restrict__ wpo,
    uint32_t* __restrict__ wp1, uint32_t* __restrict__ wp3, float* __restrict__ bnw)
{
    int i = blockIdx.x * 256 + threadIdx.x;
    if (i < 4*9*8*256) {                   // dcn_w: ((g*9+tap)*8+s)*256 + lane*4 + j
        int j = i & 3, lane = (i >> 2) & 63, s = (i >> 8) & 7;
        int r2 = i >> 11; int tap = r2 % 9, g = r2 / 9;
        int oc = g*32 + (lane & 31);
        int c  = s*16 + ((lane >> 5) << 3) + 2*j;
        wpk[i] = f2bf(dcn_w[(oc*128 + c)*9 + tap]) | (f2bf(dcn_w[(oc*128 + c + 1)*9 + tap]) << 16);
    }
    if (i < 9*8*256) {                     // off_w (27 oc pad 32): (tap*8+s)*256 + lane*4 + j
        int j = i & 3, lane = (i >> 2) & 63, s = (i >> 8) & 7, tap = i >> 11;
        int oc = lane & 31;
        int c  = s*16 + ((lane >> 5) << 3) + 2*j;
        float lo = (oc < 27) ? off_w[(oc*128 + c)*9 + tap] : 0.f;
        float hi = (oc < 27) ? off_w[(oc*128 + c + 1)*9 + tap] : 0.f;
        wpo[i] = f2bf(lo) | (f2bf(hi) << 16);
    }
    if (i < 4*16*256) {                    // cv1_w (128x256): (g*16+s)*256 + lane*4 + j
        int j = i & 3, lane = (i >> 2) & 63, s = (i >> 8) & 15, g = i >> 12;
        int oc = g*32 + (lane & 31);
        int c  = s*16 + ((lane >> 5) << 3) + 2*j;
        wp1[i] = f2bf(cv1_w[oc*256 + c]) | (f2bf(cv1_w[oc*256 + c + 1]) << 16);
    }
    if (i < 8*8*256) {                     // cv3_w (256x128): (g*8+s)*256 + lane*4 + j
        int j = i & 3, lane = (i >> 2) & 63, s = (i >> 8) & 7, g = i >> 11;
        int oc = g*32 + (lane & 31);
        int c  = s*16 + ((lane >> 5) << 3) + 2*j;
        wp3[i] = f2bf(cv3_w[oc*128 + c]) | (f2bf(cv3_w[oc*128 + c + 1]) << 16);
    }
    if (i < 128) {
        float inv = g1[i] * rsqrtf(v1[i] + 1e-5f);
        bnw[i] = inv; bnw[128+i] = b1[i] - m1[i]*inv;
    } else if (i < 256) {
        int j = i - 128;
        float inv = g2[j] * rsqrtf(v2[j] + 1e-5f);
        bnw[256+j] = inv; bnw[384+j] = b2[j] - m2[j]*inv + inv*dcn_b[j];  // fold dcn bias
    } else if (i < 512) {
        int j = i - 256;
        float inv = g3[j] * rsqrtf(v3[j] + 1e-5f);
        bnw[512+j] = inv; bnw[768+j] = b3[j] - m3[j]*inv;
    }
}

// ---------------- k1: conv1x1 (256->128, MFMA) + BN1 + SiLU -> Y2 bf16 NHWC ----------------
#define K1PAD 68
__global__ __launch_bounds__(256) void k1_cv1(
    const float* __restrict__ x, const uint32_t* __restrict__ wp1,
    const float* __restrict__ bn, uint32_t* __restrict__ y2)
{
    __shared__ uint32_t L[64*66];          // staging uses [0..16*68); epilogue transpose [64][66]
    int blk = blockIdx.x;                  // 800
    int b = blk / 100, pix0 = (blk % 100) * 64;
    int t = threadIdx.x;
    int lane = t & 63, w = t >> 6;
    int pixl = lane & 31, bhalf = lane >> 5;
    floatx16 acc0 = {}, acc1 = {};
    const float* xb = x + (size_t)b*CIN*HWX + pix0;
    const uint32_t* wpg = wp1 + (size_t)(w*16)*256 + lane*4;

    int r2 = t >> 4, c4 = (t & 15) * 4;    // staging: thread loads ch pair (2*r2,2*r2+1), 4 pix
    for (int kk = 0; kk < 256; kk += 32) {
        float4 a0 = *(const float4*)(xb + (size_t)(kk + 2*r2)*HWX + c4);
        float4 a1 = *(const float4*)(xb + (size_t)(kk + 2*r2 + 1)*HWX + c4);
        uint4 q;
        q.x = pk2f(a0.x, a1.x);
        q.y = pk2f(a0.y, a1.y);
        q.z = pk2f(a0.z, a1.z);
        q.w = pk2f(a0.w, a1.w);
        __syncthreads();                   // prev iter's frag reads done
        *(uint4*)&L[r2*K1PAD + c4] = q;
        __syncthreads();
        #pragma unroll
        for (int sl = 0; sl < 2; sl++) {
            int s = (kk >> 4) + sl;
            U8 a, b0, b1;
            const uint32_t* as = wpg + s*256;
            a.u[0]=as[0]; a.u[1]=as[1]; a.u[2]=as[2]; a.u[3]=as[3];
            int row = sl*8 + bhalf*4;
            #pragma unroll
            for (int j = 0; j < 4; j++) b0.u[j] = L[(row+j)*K1PAD + pixl];
            #pragma unroll
            for (int j = 0; j < 4; j++) b1.u[j] = L[(row+j)*K1PAD + 32 + pixl];
            acc0 = __builtin_amdgcn_mfma_f32_32x32x16_bf16(a.s, b0.s, acc0, 0, 0, 0);
            acc1 = __builtin_amdgcn_mfma_f32_32x32x16_bf16(a.s, b1.s, acc1, 0, 0, 0);
        }
    }
    __syncthreads();
    #pragma unroll
    for (int r = 0; r < 16; r += 2) {
        int oc = w*32 + (r & 3) + 8*(r >> 2) + 4*bhalf;      // even; pair (oc, oc+1)
        float s0 = bn[oc],   be0 = bn[128+oc];
        float s1 = bn[oc+1], be1 = bn[128+oc+1];
        uint32_t d0 = pk2f(silu_f(acc0[r]*s0+be0), silu_f(acc0[r+1]*s1+be1));
        uint32_t d1 = pk2f(silu_f(acc1[r]*s0+be0), silu_f(acc1[r+1]*s1+be1));
        int oc2 = oc >> 1;
        L[pixl*66 + oc2]        = d0;
        L[(32+pixl)*66 + oc2]   = d1;
    }
    __syncthreads();
    uint32_t* y2b = y2 + (size_t)b*HWX*64 + (size_t)pix0*64;
    int q2 = t & 31, p0 = t >> 5;
    #pragma unroll
    for (int pp = 0; pp < 8; pp++) {
        int pix = p0 + pp*8;
        uint2 v = make_uint2(L[pix*66 + q2*2], L[pix*66 + q2*2 + 1]);
        *(uint2*)(y2b + (size_t)pix*64 + q2*2) = v;
    }
}

// ---------------- k2: 3x3 conv (128->27, MFMA) + bias; mask sigmoided ----------------
__global__ __launch_bounds__(256) void k2_off(
    const uint32_t* __restrict__ y2, const uint32_t* __restrict__ wpo,
    const float* __restrict__ ob, float* __restrict__ pred)
{
    int blk = blockIdx.x;                  // 8 * 50
    int b = blk / 50, pix0 = (blk % 50) * 128;
    int t = threadIdx.x;
    int lane = t & 63, w = t >> 6;
    int pixl = lane & 31, half = lane >> 5;
    int p = pix0 + w*32 + pixl;
    int h = p / WID, xw = p % WID;
    const uint32_t* yb = y2 + (size_t)b*HWX*64;
    floatx16 acc = {};

    for (int tap = 0; tap < 9; tap++) {
        int dy = tap/3 - 1, dx = tap%3 - 1;
        int gh = h + dy, gx = xw + dx;
        bool valid = (gh >= 0) && (gh < HGT) && (gx >= 0) && (gx < WID);
        const uint32_t* pp = yb + (size_t)(gh*WID + gx)*64 + half*4;
        const uint32_t* ap = wpo + (size_t)(tap*8)*256 + lane*4;
        #pragma unroll
        for (int s = 0; s < 8; s++) {
            U8 a, bf;
            const uint32_t* as = ap + s*256;
            a.u[0]=as[0]; a.u[1]=as[1]; a.u[2]=as[2]; a.u[3]=as[3];
            if (valid) {
                uint4 q = *(const uint4*)(pp + s*8);
                bf.u[0]=q.x; bf.u[1]=q.y; bf.u[2]=q.z; bf.u[3]=q.w;
            } else {
                bf.u[0]=0u; bf.u[1]=0u; bf.u[2]=0u; bf.u[3]=0u;
            }
            acc = __builtin_amdgcn_mfma_f32_32x32x16_bf16(a.s, bf.s, acc, 0, 0, 0);
        }
    }
    float* pb = pred + (size_t)b*27*HWX;
    #pragma unroll
    for (int r = 0; r < 16; r++) {
        int oc = (r & 3) + 8*(r >> 2) + 4*half;
        if (oc < 27) {
            float v = acc[r] + ob[oc];
            if (oc >= 18) v = 1.f/(1.f+__expf(-v));
            pb[oc*HWX + p] = v;
        }
    }
}

// ---------------- k3: deformable conv (MFMA bf16) + BN2 + SiLU -> Z2 bf16 NHWC ----------------
// Sampler: per tap, wave handles 8 pixels as 4 passes x 2 pixels; lane = 4-ch group
// (uint2 gather, packed-fp32 bilinear via v_pk_fma_f32, v_perm bf16 pack).
#define S2S 33
__global__ __launch_bounds__(256) void k3_dcn(
    const uint32_t* __restrict__ y2, const float* __restrict__ pred,
    const uint32_t* __restrict__ wpk, const float* __restrict__ bn, uint32_t* __restrict__ z2)
{
    __shared__ uint32_t S2[64*S2S];        // 2112 dwords; epilogue reuses as [32][66]
    __shared__ int   sidx[32][4];
    __shared__ float swgt[32][4];
    int blk = blockIdx.x;                  // 1600
    int b = blk / 200, pix0 = (blk % 200) * 32;
    int t = threadIdx.x;
    int lane = t & 63, w = t >> 6;
    int pixl = lane & 31, bhalf = lane >> 5;
    const float* pb = pred + (size_t)b*27*HWX;
    const uint32_t* yb = y2 + (size_t)b*HWX*64;
    floatx16 acc = {};
    int c4 = lane & 31, pixoff = lane >> 5;

    for (int tap = 0; tap < 9; tap++) {
        __syncthreads();
        if (t < 32) {
            int pix = pix0 + t;
            int h = pix / WID, wq = pix % WID;
            float dy = pb[(2*tap)*HWX + pix];
            float dx = pb[(2*tap+1)*HWX + pix];
            float mk = pb[(18+tap)*HWX + pix];
            float pyf = (float)(h - 1 + tap/3) + dy;
            float pxf = (float)(wq - 1 + tap%3) + dx;
            float y0f = floorf(pyf), x0f = floorf(pxf);
            float wy1 = pyf - y0f, wx1 = pxf - x0f;
            int iy0 = (int)y0f, ix0 = (int)x0f;
            int iy1 = iy0 + 1,  ix1 = ix0 + 1;
            float vy0 = (iy0 >= 0 && iy0 < HGT) ? 1.f : 0.f;
            float vy1 = (iy1 >= 0 && iy1 < HGT) ? 1.f : 0.f;
            float vx0 = (ix0 >= 0 && ix0 < WID) ? 1.f : 0.f;
            float vx1 = (ix1 >= 0 && ix1 < WID) ? 1.f : 0.f;
            int cy0 = min(max(iy0,0),HGT-1), cy1 = min(max(iy1,0),HGT-1);
            int cx0 = min(max(ix0,0),WID-1), cx1 = min(max(ix1,0),WID-1);
            sidx[t][0] = cy0*WID+cx0; sidx[t][1] = cy0*WID+cx1;
            sidx[t][2] = cy1*WID+cx0; sidx[t][3] = cy1*WID+cx1;
            swgt[t][0] = (1.f-wy1)*(1.f-wx1)*mk*vy0*vx0;
            swgt[t][1] = (1.f-wy1)*wx1*mk*vy0*vx1;
            swgt[t][2] = wy1*(1.f-wx1)*mk*vy1*vx0;
            swgt[t][3] = wy1*wx1*mk*vy1*vx1;
        }
        __syncthreads();
        #pragma unroll
        for (int p = 0; p < 4; p++) {
            int pix = w*8 + p*2 + pixoff;
            int i0 = sidx[pix][0], i1 = sidx[pix][1], i2 = sidx[pix][2], i3 = sidx[pix][3];
            floatx2 W0, W1, W2, W3;
            W0.x = W0.y = swgt[pix][0]; W1.x = W1.y = swgt[pix][1];
            W2.x = W2.y = swgt[pix][2]; W3.x = W3.y = swgt[pix][3];
            uint2 u0 = *(const uint2*)(yb + (size_t)i0*64 + c4*2);
            uint2 u1 = *(const uint2*)(yb + (size_t)i1*64 + c4*2);
            uint2 u2 = *(const uint2*)(yb + (size_t)i2*64 + c4*2);
            uint2 u3 = *(const uint2*)(yb + (size_t)i3*64 + c4*2);
            floatx2 aX = up2(u0.x) * W0;
            aX = __builtin_elementwise_fma(up2(u1.x), W1, aX);
            aX = __builtin_elementwise_fma(up2(u2.x), W2, aX);
            aX = __builtin_elementwise_fma(up2(u3.x), W3, aX);
            floatx2 aY = up2(u0.y) * W0;
            aY = __builtin_elementwise_fma(up2(u1.y), W1, aY);
            aY = __builtin_elementwise_fma(up2(u2.y), W2, aY);
            aY = __builtin_elementwise_fma(up2(u3.y), W3, aY);
            S2[(c4*2)*S2S + pix]     = pk2(aX);
            S2[(c4*2 + 1)*S2S + pix] = pk2(aY);
        }
        __syncthreads();
        const uint32_t* wp = wpk + (size_t)((w*9 + tap)*8)*256 + lane*4;
        int kb = bhalf * 4;
        #pragma unroll
        for (int s = 0; s < 8; s++) {
            U8 a, bf;
            const uint32_t* wps = wp + s*256;
            a.u[0] = wps[0]; a.u[1] = wps[1]; a.u[2] = wps[2]; a.u[3] = wps[3];
            int c2b = s*8 + kb;
            bf.u[0] = S2[(c2b+0)*S2S + pixl];
            bf.u[1] = S2[(c2b+1)*S2S + pixl];
            bf.u[2] = S2[(c2b+2)*S2S + pixl];
            bf.u[3] = S2[(c2b+3)*S2S + pixl];
            acc = __builtin_amdgcn_mfma_f32_32x32x16_bf16(a.s, bf.s, acc, 0, 0, 0);
        }
    }
    __syncthreads();                       // last tap's S2 reads done
    #pragma unroll
    for (int r = 0; r < 16; r += 2) {
        int oc = w*32 + (r & 3) + 8*(r >> 2) + 4*bhalf;
        float s0 = bn[256+oc],   be0 = bn[384+oc];
        float s1 = bn[256+oc+1], be1 = bn[384+oc+1];
        uint32_t d = pk2f(silu_f(acc[r]*s0+be0), silu_f(acc[r+1]*s1+be1));
        S2[pixl*66 + (oc >> 1)] = d;
    }
    __syncthreads();
    uint32_t* z2b = z2 + (size_t)b*HWX*64 + (size_t)pix0*64;
    int q2 = t & 31, p0 = t >> 5;
    #pragma unroll
    for (int pp = 0; pp < 4; pp++) {
        int pix = p0 + pp*8;
        uint2 v = make_uint2(S2[pix*66 + q2*2], S2[pix*66 + q2*2 + 1]);
        *(uint2*)(z2b + (size_t)pix*64 + q2*2) = v;
    }
}

// ---------------- k4: conv1x1 (128->256, MFMA) + BN3 + SiLU + residual ----------------
__global__ __launch_bounds__(256) void k4_cv3(
    const uint32_t* __restrict__ z2, const uint32_t* __restrict__ wp3,
    const float* __restrict__ bn, const float* __restrict__ x, float* __restrict__ out)
{
    int blk = blockIdx.x;                  // 1600
    int half = blk & 1, blk2 = blk >> 1;
    int b = blk2 / 100, pix0 = (blk2 % 100) * 64;
    int t = threadIdx.x;
    int lane = t & 63, w = t >> 6;
    int pixl = lane & 31, bhalf = lane >> 5;
    int g = half*4 + w;
    floatx16 acc0 = {}, acc1 = {};
    const uint32_t* zb = z2 + (size_t)b*HWX*64 + (size_t)pix0*64;
    const uint32_t* wpg = wp3 + (size_t)(g*8)*256 + lane*4;

    #pragma unroll
    for (int s = 0; s < 8; s++) {
        U8 a, b0, b1;
        const uint32_t* as = wpg + s*256;
        a.u[0]=as[0]; a.u[1]=as[1]; a.u[2]=as[2]; a.u[3]=as[3];
        uint4 q0 = *(const uint4*)(zb + (size_t)pixl*64 + s*8 + bhalf*4);
        uint4 q1 = *(const uint4*)(zb + (size_t)(32+pixl)*64 + s*8 + bhalf*4);
        b0.u[0]=q0.x; b0.u[1]=q0.y; b0.u[2]=q0.z; b0.u[3]=q0.w;
        b1.u[0]=q1.x; b1.u[1]=q1.y; b1.u[2]=q1.z; b1.u[3]=q1.w;
        acc0 = __builtin_amdgcn_mfma_f32_32x32x16_bf16(a.s, b0.s, acc0, 0, 0, 0);
        acc1 = __builtin_amdgcn_mfma_f32_32x32x16_bf16(a.s, b1.s, acc1, 0, 0, 0);
    }
    const float* xb = x + (size_t)b*COUT*HWX + pix0;
    float* ob = out + (size_t)b*COUT*HWX + pix0;
    #pragma unroll
    for (int r = 0; r < 16; r++) {
        int oc = g*32 + (r & 3) + 8*(r >> 2) + 4*bhalf;
        float sc = bn[512+oc], be = bn[768+oc];
        float v0 = silu_f(acc0[r]*sc+be) + xb[(size_t)oc*HWX + pixl];
        float v1 = silu_f(acc1[r]*sc+be) + xb[(size_t)oc*HWX + 32 + pixl];
        ob[(size_t)oc*HWX + pixl]      = v0;
        ob[(size_t)oc*HWX + 32 + pixl] = v1;
    }
}

extern "C" void kernel_launch(void* const* d_in, const int* in_sizes, int n_in,
                              void* d_out, int out_size, void* d_ws, size_t ws_size,
                              hipStream_t stream) {
    const float* x     = (const float*)d_in[0];
    const float* cv1_w = (const float*)d_in[1];
    const float* bn1_g = (const float*)d_in[2];
    const float* bn1_b = (const float*)d_in[3];
    const float* bn1_m = (const float*)d_in[4];
    const float* bn1_v = (const float*)d_in[5];
    const float* off_w = (const float*)d_in[6];
    const float* off_b = (const float*)d_in[7];
    const float* dcn_w = (const float*)d_in[8];
    const float* dcn_b = (const float*)d_in[9];
    const float* bn2_g = (const float*)d_in[10];
    const float* bn2_b = (const float*)d_in[11];
    const float* bn2_m = (const float*)d_in[12];
    const float* bn2_v = (const float*)d_in[13];
    const float* cv3_w = (const float*)d_in[14];
    const float* bn3_g = (const float*)d_in[15];
    const float* bn3_b = (const float*)d_in[16];
    const float* bn3_m = (const float*)d_in[17];
    const float* bn3_v = (const float*)d_in[18];

    float* ws   = (float*)d_ws;
    float*    PRED = ws + WS_PRED;
    float*    BN   = ws + WS_BN;
    uint32_t* Y2   = (uint32_t*)(ws + WS_Y2);
    uint32_t* Z2   = (uint32_t*)(ws + WS_Z2);
    uint32_t* WPK  = (uint32_t*)(ws + WS_WPK);
    uint32_t* WPO  = (uint32_t*)(ws + WS_WPO);
    uint32_t* WP1  = (uint32_t*)(ws + WS_WP1);
    uint32_t* WP3  = (uint32_t*)(ws + WS_WP3);

    hipLaunchKernelGGL(k0_prep, dim3(288), dim3(256), 0, stream,
        dcn_w, off_w, cv1_w, cv3_w,
        bn1_g, bn1_b, bn1_m, bn1_v,
        bn2_g, bn2_b, bn2_m, bn2_v, dcn_b,
        bn3_g, bn3_b, bn3_m, bn3_v, WPK, WPO, WP1, WP3, BN);
    hipLaunchKernelGGL(k1_cv1, dim3(800), dim3(256), 0, stream, x, WP1, BN, Y2);
    hipLaunchKernelGGL(k2_off, dim3(400), dim3(256), 0, stream, Y2, WPO, off_b, PRED);
    hipLaunchKernelGGL(k3_dcn, dim3(1600), dim3(256), 0, stream, Y2, PRED, WPK, BN, Z2);
    hipLaunchKernelGGL(k4_cv3, dim3(1600), dim3(256), 0, stream, Z2, WP3, BN, x, (float*)d_out);
}

// Round 6
// 238.595 us; speedup vs baseline: 3.9830x; 1.0233x over previous
//
#include <hip/hip_runtime.h>
#include <math.h>

// Problem constants
#define HWX   6400   // 80*80
#define WID   80
#define HGT   80
#define CMID  128
#define CIN   256
#define COUT  256

// Workspace layout (float/dword offsets)
#define WS_PRED 0            // (8,27,80,80) fp32 = 1,382,400
#define WS_BN   1382400      // s1[128] b1[128] s2[128] b2[128] s3[256] b3[256] = 1024
#define WS_Y2   1383424      // (8,6400,128) bf16 NHWC = 3,276,800 dwords
#define WS_Z2   4660224      // (8,6400,128) bf16 NHWC = 3,276,800 dwords
#define WS_WPK  7937024      // dcn_w prepacked A-frags: 73,728 dwords
#define WS_WPO  8010752      // off_w prepacked A-frags: 18,432 dwords
#define WS_WP1  8029184      // cv1_w prepacked A-frags: 16,384 dwords
#define WS_WP3  8045568      // cv3_w prepacked A-frags: 16,384 dwords

typedef float floatx16 __attribute__((ext_vector_type(16)));
typedef short shortx8  __attribute__((ext_vector_type(8)));
typedef float floatx2  __attribute__((ext_vector_type(2)));

union U8 { uint32_t u[4]; shortx8 s; };

__device__ __forceinline__ float silu_f(float t){ return t / (1.f + __expf(-t)); }
__device__ __forceinline__ uint32_t f2bf(float f){           // RNE fp32->bf16 (cold paths)
    uint32_t u = __float_as_uint(f);
    return (u + 0x7fffu + ((u >> 16) & 1u)) >> 16;
}
// unpack bf16x2 dword -> float2 (lo, hi)
__device__ __forceinline__ floatx2 up2(uint32_t u){
    floatx2 r; r.x = __uint_as_float(u << 16); r.y = __uint_as_float(u & 0xffff0000u); return r;
}
// pack float2 -> bf16x2 dword (round-half-up: +0x8000 then take high halves via v_perm)
__device__ __forceinline__ uint32_t pk2(floatx2 v){
    return __builtin_amdgcn_perm(__float_as_uint(v.y) + 0x8000u,
                                 __float_as_uint(v.x) + 0x8000u, 0x07060302u);
}
__device__ __forceinline__ uint32_t pk2f(float a, float b){ floatx2 v; v.x=a; v.y=b; return pk2(v); }

// ---------------- prep: BN fold + MFMA weight prepacks ----------------
// A-frag convention (verified): lane's oc = g*32 + (lane&31);
// k-index c = s*16 + (lane>>5)*8 + 2j (+1 in hi half of dword j).
__global__ __launch_bounds__(256) void k0_prep(
    const float* __restrict__ dcn_w, const float* __restrict__ off_w,
    const float* __restrict__ cv1_w, const float* __restrict__ cv3_w,
    const float* __restrict__ g1, const float* __restrict__ b1, const float* __restrict__ m1, const float* __restrict__ v1,
    const float* __restrict__ g2, const float* __restrict__ b2, const float* __restrict__ m2, const float* __restrict__ v2,
    const float* __restrict__ dcn_b,
    const float* __restrict__ g3, const float* __restrict__ b3, const float* __restrict__ m3, const float* __restrict__ v3,
    uint32_t* __restrict__ wpk, uint32_t* __restrict__ wpo,
    uint32_t* __restrict__ wp1, uint32_t* __restrict__ wp3, float* __restrict__ bnw)
{
    int i = blockIdx.x * 256 + threadIdx.x;
    if (i < 4*9*8*256) {                   // dcn_w: ((g*9+tap)*8+s)*256 + lane*4 + j
        int j = i & 3, lane = (i >> 2) & 63, s = (i >> 8) & 7;
        int r2 = i >> 11; int tap = r2 % 9, g = r2 / 9;
        int oc = g*32 + (lane & 31);
        int c  = s*16 + ((lane >> 5) << 3) + 2*j;
        wpk[i] = f2bf(dcn_w[(oc*128 + c)*9 + tap]) | (f2bf(dcn_w[(oc*128 + c + 1)*9 + tap]) << 16);
    }
    if (i < 9*8*256) {                     // off_w (27 oc pad 32): (tap*8+s)*256 + lane*4 + j
        int j = i & 3, lane = (i >> 2) & 63, s = (i >> 8) & 7, tap = i >> 11;
        int oc = lane & 31;
        int c  = s*16 + ((lane >> 5) << 3) + 2*j;
        float lo = (oc < 27) ? off_w[(oc*128 + c)*9 + tap] : 0.f;
        float hi = (oc < 27) ? off_w[(oc*128 + c + 1)*9 + tap] : 0.f;
        wpo[i] = f2bf(lo) | (f2bf(hi) << 16);
    }
    if (i < 4*16*256) {                    // cv1_w (128x256): (g*16+s)*256 + lane*4 + j
        int j = i & 3, lane = (i >> 2) & 63, s = (i >> 8) & 15, g = i >> 12;
        int oc = g*32 + (lane & 31);
        int c  = s*16 + ((lane >> 5) << 3) + 2*j;
        wp1[i] = f2bf(cv1_w[oc*256 + c]) | (f2bf(cv1_w[oc*256 + c + 1]) << 16);
    }
    if (i < 8*8*256) {                     // cv3_w (256x128): (g*8+s)*256 + lane*4 + j
        int j = i & 3, lane = (i >> 2) & 63, s = (i >> 8) & 7, g = i >> 11;
        int oc = g*32 + (lane & 31);
        int c  = s*16 + ((lane >> 5) << 3) + 2*j;
        wp3[i] = f2bf(cv3_w[oc*128 + c]) | (f2bf(cv3_w[oc*128 + c + 1]) << 16);
    }
    if (i < 128) {
        float inv = g1[i] * rsqrtf(v1[i] + 1e-5f);
        bnw[i] = inv; bnw[128+i] = b1[i] - m1[i]*inv;
    } else if (i < 256) {
        int j = i - 128;
        float inv = g2[j] * rsqrtf(v2[j] + 1e-5f);
        bnw[256+j] = inv; bnw[384+j] = b2[j] - m2[j]*inv + inv*dcn_b[j];  // fold dcn bias
    } else if (i < 512) {
        int j = i - 256;
        float inv = g3[j] * rsqrtf(v3[j] + 1e-5f);
        bnw[512+j] = inv; bnw[768+j] = b3[j] - m3[j]*inv;
    }
}

// ---------------- k1: conv1x1 (256->128, MFMA) + BN1 + SiLU -> Y2 bf16 NHWC ----------------
#define K1PAD 68
__global__ __launch_bounds__(256) void k1_cv1(
    const float* __restrict__ x, const uint32_t* __restrict__ wp1,
    const float* __restrict__ bn, uint32_t* __restrict__ y2)
{
    __shared__ __align__(16) uint32_t L[64*66];  // staging [0..16*68); epilogue transpose [64][66]
    int blk = blockIdx.x;                  // 800
    int b = blk / 100, pix0 = (blk % 100) * 64;
    int t = threadIdx.x;
    int lane = t & 63, w = t >> 6;
    int pixl = lane & 31, bhalf = lane >> 5;
    floatx16 acc0 = {}, acc1 = {};
    const float* xb = x + (size_t)b*CIN*HWX + pix0;
    const uint32_t* wpg = wp1 + (size_t)(w*16)*256 + lane*4;

    int r2 = t >> 4, c4 = (t & 15) * 4;    // staging: thread loads ch pair (2*r2,2*r2+1), 4 pix
    for (int kk = 0; kk < 256; kk += 32) {
        float4 a0 = *(const float4*)(xb + (size_t)(kk + 2*r2)*HWX + c4);
        float4 a1 = *(const float4*)(xb + (size_t)(kk + 2*r2 + 1)*HWX + c4);
        uint4 q;
        q.x = pk2f(a0.x, a1.x);
        q.y = pk2f(a0.y, a1.y);
        q.z = pk2f(a0.z, a1.z);
        q.w = pk2f(a0.w, a1.w);
        __syncthreads();                   // prev iter's frag reads done
        *(uint4*)&L[r2*K1PAD + c4] = q;
        __syncthreads();
        #pragma unroll
        for (int sl = 0; sl < 2; sl++) {
            int s = (kk >> 4) + sl;
            U8 a, b0, b1;
            const uint32_t* as = wpg + s*256;
            a.u[0]=as[0]; a.u[1]=as[1]; a.u[2]=as[2]; a.u[3]=as[3];
            int row = sl*8 + bhalf*4;
            #pragma unroll
            for (int j = 0; j < 4; j++) b0.u[j] = L[(row+j)*K1PAD + pixl];
            #pragma unroll
            for (int j = 0; j < 4; j++) b1.u[j] = L[(row+j)*K1PAD + 32 + pixl];
            acc0 = __builtin_amdgcn_mfma_f32_32x32x16_bf16(a.s, b0.s, acc0, 0, 0, 0);
            acc1 = __builtin_amdgcn_mfma_f32_32x32x16_bf16(a.s, b1.s, acc1, 0, 0, 0);
        }
    }
    __syncthreads();
    #pragma unroll
    for (int r = 0; r < 16; r += 2) {
        int oc = w*32 + (r & 3) + 8*(r >> 2) + 4*bhalf;      // even; pair (oc, oc+1)
        float s0 = bn[oc],   be0 = bn[128+oc];
        float s1 = bn[oc+1], be1 = bn[128+oc+1];
        uint32_t d0 = pk2f(silu_f(acc0[r]*s0+be0), silu_f(acc0[r+1]*s1+be1));
        uint32_t d1 = pk2f(silu_f(acc1[r]*s0+be0), silu_f(acc1[r+1]*s1+be1));
        int oc2 = oc >> 1;
        L[pixl*66 + oc2]        = d0;
        L[(32+pixl)*66 + oc2]   = d1;
    }
    __syncthreads();
    uint32_t* y2b = y2 + (size_t)b*HWX*64 + (size_t)pix0*64;
    int q2 = t & 31, p0 = t >> 5;
    #pragma unroll
    for (int pp = 0; pp < 8; pp++) {
        int pix = p0 + pp*8;
        uint2 v = make_uint2(L[pix*66 + q2*2], L[pix*66 + q2*2 + 1]);
        *(uint2*)(y2b + (size_t)pix*64 + q2*2) = v;
    }
}

// ---------------- k2: 3x3 conv (128->27, MFMA) + bias; mask sigmoided ----------------
__global__ __launch_bounds__(256) void k2_off(
    const uint32_t* __restrict__ y2, const uint32_t* __restrict__ wpo,
    const float* __restrict__ ob, float* __restrict__ pred)
{
    int blk = blockIdx.x;                  // 8 * 50
    int b = blk / 50, pix0 = (blk % 50) * 128;
    int t = threadIdx.x;
    int lane = t & 63, w = t >> 6;
    int pixl = lane & 31, half = lane >> 5;
    int p = pix0 + w*32 + pixl;
    int h = p / WID, xw = p % WID;
    const uint32_t* yb = y2 + (size_t)b*HWX*64;
    floatx16 acc = {};

    for (int tap = 0; tap < 9; tap++) {
        int dy = tap/3 - 1, dx = tap%3 - 1;
        int gh = h + dy, gx = xw + dx;
        bool valid = (gh >= 0) && (gh < HGT) && (gx >= 0) && (gx < WID);
        const uint32_t* pp = yb + (size_t)(gh*WID + gx)*64 + half*4;
        const uint32_t* ap = wpo + (size_t)(tap*8)*256 + lane*4;
        #pragma unroll
        for (int s = 0; s < 8; s++) {
            U8 a, bf;
            const uint32_t* as = ap + s*256;
            a.u[0]=as[0]; a.u[1]=as[1]; a.u[2]=as[2]; a.u[3]=as[3];
            if (valid) {
                uint4 q = *(const uint4*)(pp + s*8);
                bf.u[0]=q.x; bf.u[1]=q.y; bf.u[2]=q.z; bf.u[3]=q.w;
            } else {
                bf.u[0]=0u; bf.u[1]=0u; bf.u[2]=0u; bf.u[3]=0u;
            }
            acc = __builtin_amdgcn_mfma_f32_32x32x16_bf16(a.s, bf.s, acc, 0, 0, 0);
        }
    }
    float* pb = pred + (size_t)b*27*HWX;
    #pragma unroll
    for (int r = 0; r < 16; r++) {
        int oc = (r & 3) + 8*(r >> 2) + 4*half;
        if (oc < 27) {
            float v = acc[r] + ob[oc];
            if (oc >= 18) v = 1.f/(1.f+__expf(-v));
            pb[oc*HWX + p] = v;
        }
    }
}

// ---------------- k3: deformable conv (MFMA bf16, software-pipelined) ----------------
// Params for all 9 taps hoisted (one parallel phase). Per tap: ONE barrier;
// tap t+1 gathers issue before tap t's MFMA phase (latency hidden under MFMA).
// S2 pix-major [32][68]: sampler write = ds_write_b64, B-frag = ds_read_b128.
#define S2R 68
__global__ __launch_bounds__(256) void k3_dcn(
    const uint32_t* __restrict__ y2, const float* __restrict__ pred,
    const uint32_t* __restrict__ wpk, const float* __restrict__ bn, uint32_t* __restrict__ z2)
{
    __shared__ __align__(16) uint32_t S2[2][32*S2R];   // 17408 B
    __shared__ __align__(16) int   sidx9[9*32*4];      // 4608 B
    __shared__ __align__(16) float swgt9[9*32*4];      // 4608 B
    int blk = blockIdx.x;                  // 1600
    int b = blk / 200, pix0 = (blk % 200) * 32;
    int t = threadIdx.x;
    int lane = t & 63, w = t >> 6;
    int pixl = lane & 31, bhalf = lane >> 5;
    const float* pb = pred + (size_t)b*27*HWX;
    const uint32_t* yb = y2 + (size_t)b*HWX*64;
    floatx16 acc = {};
    int c4 = lane & 31, pixoff = lane >> 5;

    // ---- phase 0: all bilinear params, 288 items across 256 threads ----
    for (int it = t; it < 288; it += 256) {
        int tap = it >> 5, px = it & 31;
        int pix = pix0 + px;
        int h = pix / WID, wq = pix % WID;
        float dy = pb[(2*tap)*HWX + pix];
        float dx = pb[(2*tap+1)*HWX + pix];
        float mk = pb[(18+tap)*HWX + pix];
        float pyf = (float)(h - 1 + tap/3) + dy;
        float pxf = (float)(wq - 1 + tap%3) + dx;
        float y0f = floorf(pyf), x0f = floorf(pxf);
        float wy1 = pyf - y0f, wx1 = pxf - x0f;
        int iy0 = (int)y0f, ix0 = (int)x0f;
        int iy1 = iy0 + 1,  ix1 = ix0 + 1;
        float vy0 = (iy0 >= 0 && iy0 < HGT) ? 1.f : 0.f;
        float vy1 = (iy1 >= 0 && iy1 < HGT) ? 1.f : 0.f;
        float vx0 = (ix0 >= 0 && ix0 < WID) ? 1.f : 0.f;
        float vx1 = (ix1 >= 0 && ix1 < WID) ? 1.f : 0.f;
        int cy0 = min(max(iy0,0),HGT-1), cy1 = min(max(iy1,0),HGT-1);
        int cx0 = min(max(ix0,0),WID-1), cx1 = min(max(ix1,0),WID-1);
        int base = (tap*32 + px)*4;
        sidx9[base+0] = cy0*WID+cx0; sidx9[base+1] = cy0*WID+cx1;
        sidx9[base+2] = cy1*WID+cx0; sidx9[base+3] = cy1*WID+cx1;
        swgt9[base+0] = (1.f-wy1)*(1.f-wx1)*mk*vy0*vx0;
        swgt9[base+1] = (1.f-wy1)*wx1*mk*vy0*vx1;
        swgt9[base+2] = wy1*(1.f-wx1)*mk*vy1*vx0;
        swgt9[base+3] = wy1*wx1*mk*vy1*vx1;
    }
    __syncthreads();

    uint2  u[4][4];      // [pass][corner] gathered channel data (this lane's 4 ch)
    float4 W[4];         // [pass] bilinear weights
    uint2  samp[4];      // [pass] packed bf16x2 x2 sampled output

    // prologue gather+compute for tap 0
    #pragma unroll
    for (int p = 0; p < 4; p++) {
        int pix = w*8 + p*2 + pixoff;
        int base = (0*32 + pix)*4;
        int4 si = *(const int4*)&sidx9[base];
        W[p] = *(const float4*)&swgt9[base];
        u[p][0] = *(const uint2*)(yb + (size_t)si.x*64 + c4*2);
        u[p][1] = *(const uint2*)(yb + (size_t)si.y*64 + c4*2);
        u[p][2] = *(const uint2*)(yb + (size_t)si.z*64 + c4*2);
        u[p][3] = *(const uint2*)(yb + (size_t)si.w*64 + c4*2);
    }
    #pragma unroll
    for (int p = 0; p < 4; p++) {
        floatx2 W0, W1, W2, W3;
        W0.x = W0.y = W[p].x; W1.x = W1.y = W[p].y;
        W2.x = W2.y = W[p].z; W3.x = W3.y = W[p].w;
        floatx2 aX = up2(u[p][0].x) * W0;
        aX = __builtin_elementwise_fma(up2(u[p][1].x), W1, aX);
        aX = __builtin_elementwise_fma(up2(u[p][2].x), W2, aX);
        aX = __builtin_elementwise_fma(up2(u[p][3].x), W3, aX);
        floatx2 aY = up2(u[p][0].y) * W0;
        aY = __builtin_elementwise_fma(up2(u[p][1].y), W1, aY);
        aY = __builtin_elementwise_fma(up2(u[p][2].y), W2, aY);
        aY = __builtin_elementwise_fma(up2(u[p][3].y), W3, aY);
        samp[p].x = pk2(aX); samp[p].y = pk2(aY);
    }

    #pragma unroll
    for (int tap = 0; tap < 9; tap++) {
        uint32_t* S = &S2[tap & 1][0];
        // write this tap's samples (ds_write_b64, pix-major)
        #pragma unroll
        for (int p = 0; p < 4; p++) {
            int pix = w*8 + p*2 + pixoff;
            *(uint2*)&S[pix*S2R + c4*2] = samp[p];
        }
        __syncthreads();
        // issue next tap's gathers NOW (latency hides under MFMA below)
        if (tap < 8) {
            #pragma unroll
            for (int p = 0; p < 4; p++) {
                int pix = w*8 + p*2 + pixoff;
                int base = ((tap+1)*32 + pix)*4;
                int4 si = *(const int4*)&sidx9[base];
                W[p] = *(const float4*)&swgt9[base];
                u[p][0] = *(const uint2*)(yb + (size_t)si.x*64 + c4*2);
                u[p][1] = *(const uint2*)(yb + (size_t)si.y*64 + c4*2);
                u[p][2] = *(const uint2*)(yb + (size_t)si.z*64 + c4*2);
                u[p][3] = *(const uint2*)(yb + (size_t)si.w*64 + c4*2);
            }
        }
        // MFMA phase: 8 K-steps, B = ds_read_b128 from pix-major S2
        const uint32_t* wp = wpk + (size_t)((w*9 + tap)*8)*256 + lane*4;
        #pragma unroll
        for (int s = 0; s < 8; s++) {
            U8 a, bf;
            const uint32_t* wps = wp + s*256;
            a.u[0] = wps[0]; a.u[1] = wps[1]; a.u[2] = wps[2]; a.u[3] = wps[3];
            uint4 q = *(const uint4*)&S[pixl*S2R + s*8 + bhalf*4];
            bf.u[0]=q.x; bf.u[1]=q.y; bf.u[2]=q.z; bf.u[3]=q.w;
            acc = __builtin_amdgcn_mfma_f32_32x32x16_bf16(a.s, bf.s, acc, 0, 0, 0);
        }
        // compute next tap's samples (waits on the gathers issued above)
        if (tap < 8) {
            #pragma unroll
            for (int p = 0; p < 4; p++) {
                floatx2 W0, W1, W2, W3;
                W0.x = W0.y = W[p].x; W1.x = W1.y = W[p].y;
                W2.x = W2.y = W[p].z; W3.x = W3.y = W[p].w;
                floatx2 aX = up2(u[p][0].x) * W0;
                aX = __builtin_elementwise_fma(up2(u[p][1].x), W1, aX);
                aX = __builtin_elementwise_fma(up2(u[p][2].x), W2, aX);
                aX = __builtin_elementwise_fma(up2(u[p][3].x), W3, aX);
                floatx2 aY = up2(u[p][0].y) * W0;
                aY = __builtin_elementwise_fma(up2(u[p][1].y), W1, aY);
                aY = __builtin_elementwise_fma(up2(u[p][2].y), W2, aY);
                aY = __builtin_elementwise_fma(up2(u[p][3].y), W3, aY);
                samp[p].x = pk2(aX); samp[p].y = pk2(aY);
            }
        }
    }
    // epilogue: BN2+SiLU into S2[1] (tap 8 consumed S2[0]; S2[1] reads done pre-barrier)
    uint32_t* SE = &S2[1][0];
    #pragma unroll
    for (int r = 0; r < 16; r += 2) {
        int oc = w*32 + (r & 3) + 8*(r >> 2) + 4*bhalf;
        float s0 = bn[256+oc],   be0 = bn[384+oc];
        float s1 = bn[256+oc+1], be1 = bn[384+oc+1];
        SE[pixl*S2R + (oc >> 1)] = pk2f(silu_f(acc[r]*s0+be0), silu_f(acc[r+1]*s1+be1));
    }
    __syncthreads();
    uint32_t* z2b = z2 + (size_t)b*HWX*64 + (size_t)pix0*64;
    int q2 = t & 31, p0 = t >> 5;
    #pragma unroll
    for (int pp = 0; pp < 4; pp++) {
        int pix = p0 + pp*8;
        uint2 v = *(const uint2*)&SE[pix*S2R + q2*2];
        *(uint2*)(z2b + (size_t)pix*64 + q2*2) = v;
    }
}

// ---------------- k4: conv1x1 (128->256, MFMA) + BN3 + SiLU + residual ----------------
__global__ __launch_bounds__(256) void k4_cv3(
    const uint32_t* __restrict__ z2, const uint32_t* __restrict__ wp3,
    const float* __restrict__ bn, const float* __restrict__ x, float* __restrict__ out)
{
    int blk = blockIdx.x;                  // 1600
    int half = blk & 1, blk2 = blk >> 1;
    int b = blk2 / 100, pix0 = (blk2 % 100) * 64;
    int t = threadIdx.x;
    int lane = t & 63, w = t >> 6;
    int pixl = lane & 31, bhalf = lane >> 5;
    int g = half*4 + w;
    floatx16 acc0 = {}, acc1 = {};
    const uint32_t* zb = z2 + (size_t)b*HWX*64 + (size_t)pix0*64;
    const uint32_t* wpg = wp3 + (size_t)(g*8)*256 + lane*4;

    #pragma unroll
    for (int s = 0; s < 8; s++) {
        U8 a, b0, b1;
        const uint32_t* as = wpg + s*256;
        a.u[0]=as[0]; a.u[1]=as[1]; a.u[2]=as[2]; a.u[3]=as[3];
        uint4 q0 = *(const uint4*)(zb + (size_t)pixl*64 + s*8 + bhalf*4);
        uint4 q1 = *(const uint4*)(zb + (size_t)(32+pixl)*64 + s*8 + bhalf*4);
        b0.u[0]=q0.x; b0.u[1]=q0.y; b0.u[2]=q0.z; b0.u[3]=q0.w;
        b1.u[0]=q1.x; b1.u[1]=q1.y; b1.u[2]=q1.z; b1.u[3]=q1.w;
        acc0 = __builtin_amdgcn_mfma_f32_32x32x16_bf16(a.s, b0.s, acc0, 0, 0, 0);
        acc1 = __builtin_amdgcn_mfma_f32_32x32x16_bf16(a.s, b1.s, acc1, 0, 0, 0);
    }
    const float* xb = x + (size_t)b*COUT*HWX + pix0;
    float* ob = out + (size_t)b*COUT*HWX + pix0;
    #pragma unroll
    for (int r = 0; r < 16; r++) {
        int oc = g*32 + (r & 3) + 8*(r >> 2) + 4*bhalf;
        float sc = bn[512+oc], be = bn[768+oc];
        float v0 = silu_f(acc0[r]*sc+be) + xb[(size_t)oc*HWX + pixl];
        float v1 = silu_f(acc1[r]*sc+be) + xb[(size_t)oc*HWX + 32 + pixl];
        ob[(size_t)oc*HWX + pixl]      = v0;
        ob[(size_t)oc*HWX + 32 + pixl] = v1;
    }
}

extern "C" void kernel_launch(void* const* d_in, const int* in_sizes, int n_in,
                              void* d_out, int out_size, void* d_ws, size_t ws_size,
                              hipStream_t stream) {
    const float* x     = (const float*)d_in[0];
    const float* cv1_w = (const float*)d_in[1];
    const float* bn1_g = (const float*)d_in[2];
    const float* bn1_b = (const float*)d_in[3];
    const float* bn1_m = (const float*)d_in[4];
    const float* bn1_v = (const float*)d_in[5];
    const float* off_w = (const float*)d_in[6];
    const float* off_b = (const float*)d_in[7];
    const float* dcn_w = (const float*)d_in[8];
    const float* dcn_b = (const float*)d_in[9];
    const float* bn2_g = (const float*)d_in[10];
    const float* bn2_b = (const float*)d_in[11];
    const float* bn2_m = (const float*)d_in[12];
    const float* bn2_v = (const float*)d_in[13];
    const float* cv3_w = (const float*)d_in[14];
    const float* bn3_g = (const float*)d_in[15];
    const float* bn3_b = (const float*)d_in[16];
    const float* bn3_m = (const float*)d_in[17];
    const float* bn3_v = (const float*)d_in[18];

    float* ws   = (float*)d_ws;
    float*    PRED = ws + WS_PRED;
    float*    BN   = ws + WS_BN;
    uint32_t* Y2   = (uint32_t*)(ws + WS_Y2);
    uint32_t* Z2   = (uint32_t*)(ws + WS_Z2);
    uint32_t* WPK  = (uint32_t*)(ws + WS_WPK);
    uint32_t* WPO  = (uint32_t*)(ws + WS_WPO);
    uint32_t* WP1  = (uint32_t*)(ws + WS_WP1);
    uint32_t* WP3  = (uint32_t*)(ws + WS_WP3);

    hipLaunchKernelGGL(k0_prep, dim3(288), dim3(256), 0, stream,
        dcn_w, off_w, cv1_w, cv3_w,
        bn1_g, bn1_b, bn1_m, bn1_v,
        bn2_g, bn2_b, bn2_m, bn2_v, dcn_b,
        bn3_g, bn3_b, bn3_m, bn3_v, WPK, WPO, WP1, WP3, BN);
    hipLaunchKernelGGL(k1_cv1, dim3(800), dim3(256), 0, stream, x, WP1, BN, Y2);
    hipLaunchKernelGGL(k2_off, dim3(400), dim3(256), 0, stream, Y2, WPO, off_b, PRED);
    hipLaunchKernelGGL(k3_dcn, dim3(1600), dim3(256), 0, stream, Y2, PRED, WPK, BN, Z2);
    hipLaunchKernelGGL(k4_cv3, dim3(1600), dim3(256), 0, stream, Z2, WP3, BN, x, (float*)d_out);
}

// Round 7
// 235.042 us; speedup vs baseline: 4.0432x; 1.0151x over previous
//
#include <hip/hip_runtime.h>
#include <math.h>

// Problem constants
#define HWX   6400   // 80*80
#define WID   80
#define HGT   80
#define CMID  128
#define CIN   256
#define COUT  256

// Workspace layout (float/dword offsets)
#define WS_BN   0            // s1[128] b1[128] s2[128] b2[128] s3[256] b3[256] = 1024
#define WS_Y2   1024         // (8,6400,128) bf16 NHWC = 3,276,800 dwords
#define WS_Z2   3277824      // (8,6400,128) bf16 NHWC = 3,276,800 dwords
#define WS_WPK  6554624      // dcn_w prepacked A-frags: 73,728 dwords
#define WS_WPO  6628352      // off_w prepacked A-frags: 18,432 dwords
#define WS_WP1  6646784      // cv1_w prepacked A-frags: 16,384 dwords
#define WS_WP3  6663168      // cv3_w prepacked A-frags: 16,384 dwords

typedef float floatx16 __attribute__((ext_vector_type(16)));
typedef short shortx8  __attribute__((ext_vector_type(8)));
typedef float floatx2  __attribute__((ext_vector_type(2)));

union U8 { uint32_t u[4]; shortx8 s; };

__device__ __forceinline__ float silu_f(float t){ return t / (1.f + __expf(-t)); }
__device__ __forceinline__ uint32_t f2bf(float f){           // RNE fp32->bf16 (cold paths)
    uint32_t u = __float_as_uint(f);
    return (u + 0x7fffu + ((u >> 16) & 1u)) >> 16;
}
// unpack bf16x2 dword -> float2 (lo, hi)
__device__ __forceinline__ floatx2 up2(uint32_t u){
    floatx2 r; r.x = __uint_as_float(u << 16); r.y = __uint_as_float(u & 0xffff0000u); return r;
}
// pack float2 -> bf16x2 dword (round-half-up: +0x8000 then take high halves via v_perm)
__device__ __forceinline__ uint32_t pk2(floatx2 v){
    return __builtin_amdgcn_perm(__float_as_uint(v.y) + 0x8000u,
                                 __float_as_uint(v.x) + 0x8000u, 0x07060302u);
}
__device__ __forceinline__ uint32_t pk2f(float a, float b){ floatx2 v; v.x=a; v.y=b; return pk2(v); }

// ---------------- prep: BN fold + MFMA weight prepacks ----------------
// A-frag convention (verified): lane's oc = g*32 + (lane&31);
// k-index c = s*16 + (lane>>5)*8 + 2j (+1 in hi half of dword j).
__global__ __launch_bounds__(256) void k0_prep(
    const float* __restrict__ dcn_w, const float* __restrict__ off_w,
    const float* __restrict__ cv1_w, const float* __restrict__ cv3_w,
    const float* __restrict__ g1, const float* __restrict__ b1, const float* __restrict__ m1, const float* __restrict__ v1,
    const float* __restrict__ g2, const float* __restrict__ b2, const float* __restrict__ m2, const float* __restrict__ v2,
    const float* __restrict__ dcn_b,
    const float* __restrict__ g3, const float* __restrict__ b3, const float* __restrict__ m3, const float* __restrict__ v3,
    uint32_t* __restrict__ wpk, uint32_t* __restrict__ wpo,
    uint32_t* __restrict__ wp1, uint32_t* __restrict__ wp3, float* __restrict__ bnw)
{
    int i = blockIdx.x * 256 + threadIdx.x;
    if (i < 4*9*8*256) {                   // dcn_w: ((g*9+tap)*8+s)*256 + lane*4 + j
        int j = i & 3, lane = (i >> 2) & 63, s = (i >> 8) & 7;
        int r2 = i >> 11; int tap = r2 % 9, g = r2 / 9;
        int oc = g*32 + (lane & 31);
        int c  = s*16 + ((lane >> 5) << 3) + 2*j;
        wpk[i] = f2bf(dcn_w[(oc*128 + c)*9 + tap]) | (f2bf(dcn_w[(oc*128 + c + 1)*9 + tap]) << 16);
    }
    if (i < 9*8*256) {                     // off_w (27 oc pad 32): (tap*8+s)*256 + lane*4 + j
        int j = i & 3, lane = (i >> 2) & 63, s = (i >> 8) & 7, tap = i >> 11;
        int oc = lane & 31;
        int c  = s*16 + ((lane >> 5) << 3) + 2*j;
        float lo = (oc < 27) ? off_w[(oc*128 + c)*9 + tap] : 0.f;
        float hi = (oc < 27) ? off_w[(oc*128 + c + 1)*9 + tap] : 0.f;
        wpo[i] = f2bf(lo) | (f2bf(hi) << 16);
    }
    if (i < 4*16*256) {                    // cv1_w (128x256): (g*16+s)*256 + lane*4 + j
        int j = i & 3, lane = (i >> 2) & 63, s = (i >> 8) & 15, g = i >> 12;
        int oc = g*32 + (lane & 31);
        int c  = s*16 + ((lane >> 5) << 3) + 2*j;
        wp1[i] = f2bf(cv1_w[oc*256 + c]) | (f2bf(cv1_w[oc*256 + c + 1]) << 16);
    }
    if (i < 8*8*256) {                     // cv3_w (256x128): (g*8+s)*256 + lane*4 + j
        int j = i & 3, lane = (i >> 2) & 63, s = (i >> 8) & 7, g = i >> 11;
        int oc = g*32 + (lane & 31);
        int c  = s*16 + ((lane >> 5) << 3) + 2*j;
        wp3[i] = f2bf(cv3_w[oc*128 + c]) | (f2bf(cv3_w[oc*128 + c + 1]) << 16);
    }
    if (i < 128) {
        float inv = g1[i] * rsqrtf(v1[i] + 1e-5f);
        bnw[i] = inv; bnw[128+i] = b1[i] - m1[i]*inv;
    } else if (i < 256) {
        int j = i - 128;
        float inv = g2[j] * rsqrtf(v2[j] + 1e-5f);
        bnw[256+j] = inv; bnw[384+j] = b2[j] - m2[j]*inv + inv*dcn_b[j];  // fold dcn bias
    } else if (i < 512) {
        int j = i - 256;
        float inv = g3[j] * rsqrtf(v3[j] + 1e-5f);
        bnw[512+j] = inv; bnw[768+j] = b3[j] - m3[j]*inv;
    }
}

// ---------------- k1: conv1x1 (256->128, MFMA) + BN1 + SiLU -> Y2 bf16 NHWC ----------------
#define K1PAD 68
__global__ __launch_bounds__(256) void k1_cv1(
    const float* __restrict__ x, const uint32_t* __restrict__ wp1,
    const float* __restrict__ bn, uint32_t* __restrict__ y2)
{
    __shared__ __align__(16) uint32_t L[64*66];  // staging [0..16*68); epilogue transpose [64][66]
    int blk = blockIdx.x;                  // 800
    int b = blk / 100, pix0 = (blk % 100) * 64;
    int t = threadIdx.x;
    int lane = t & 63, w = t >> 6;
    int pixl = lane & 31, bhalf = lane >> 5;
    floatx16 acc0 = {}, acc1 = {};
    const float* xb = x + (size_t)b*CIN*HWX + pix0;
    const uint32_t* wpg = wp1 + (size_t)(w*16)*256 + lane*4;

    int r2 = t >> 4, c4 = (t & 15) * 4;    // staging: thread loads ch pair (2*r2,2*r2+1), 4 pix
    for (int kk = 0; kk < 256; kk += 32) {
        float4 a0 = *(const float4*)(xb + (size_t)(kk + 2*r2)*HWX + c4);
        float4 a1 = *(const float4*)(xb + (size_t)(kk + 2*r2 + 1)*HWX + c4);
        uint4 q;
        q.x = pk2f(a0.x, a1.x);
        q.y = pk2f(a0.y, a1.y);
        q.z = pk2f(a0.z, a1.z);
        q.w = pk2f(a0.w, a1.w);
        __syncthreads();                   // prev iter's frag reads done
        *(uint4*)&L[r2*K1PAD + c4] = q;
        __syncthreads();
        #pragma unroll
        for (int sl = 0; sl < 2; sl++) {
            int s = (kk >> 4) + sl;
            U8 a, b0, b1;
            const uint32_t* as = wpg + s*256;
            a.u[0]=as[0]; a.u[1]=as[1]; a.u[2]=as[2]; a.u[3]=as[3];
            int row = sl*8 + bhalf*4;
            #pragma unroll
            for (int j = 0; j < 4; j++) b0.u[j] = L[(row+j)*K1PAD + pixl];
            #pragma unroll
            for (int j = 0; j < 4; j++) b1.u[j] = L[(row+j)*K1PAD + 32 + pixl];
            acc0 = __builtin_amdgcn_mfma_f32_32x32x16_bf16(a.s, b0.s, acc0, 0, 0, 0);
            acc1 = __builtin_amdgcn_mfma_f32_32x32x16_bf16(a.s, b1.s, acc1, 0, 0, 0);
        }
    }
    __syncthreads();
    #pragma unroll
    for (int r = 0; r < 16; r += 2) {
        int oc = w*32 + (r & 3) + 8*(r >> 2) + 4*bhalf;      // even; pair (oc, oc+1)
        float s0 = bn[oc],   be0 = bn[128+oc];
        float s1 = bn[oc+1], be1 = bn[128+oc+1];
        uint32_t d0 = pk2f(silu_f(acc0[r]*s0+be0), silu_f(acc0[r+1]*s1+be1));
        uint32_t d1 = pk2f(silu_f(acc1[r]*s0+be0), silu_f(acc1[r+1]*s1+be1));
        int oc2 = oc >> 1;
        L[pixl*66 + oc2]        = d0;
        L[(32+pixl)*66 + oc2]   = d1;
    }
    __syncthreads();
    uint32_t* y2b = y2 + (size_t)b*HWX*64 + (size_t)pix0*64;
    int q2 = t & 31, p0 = t >> 5;
    #pragma unroll
    for (int pp = 0; pp < 8; pp++) {
        int pix = p0 + pp*8;
        uint2 v = make_uint2(L[pix*66 + q2*2], L[pix*66 + q2*2 + 1]);
        *(uint2*)(y2b + (size_t)pix*64 + q2*2) = v;
    }
}

// ---------------- k3: fused offset-conv + deformable conv (MFMA bf16) ----------------
// Phase A: this block's 32 pixels' offset/mask pred (3x3 conv 128->27), taps
// split 2/2/2/3 across the 4 waves, partials reduced via LDS. Phase B: params.
// Phase C: software-pipelined dcn main loop (1 barrier/tap, gathers prefetch
// under MFMA). S2 pix-major [32][68]: ds_write_b64 sampler, ds_read_b128 B-frag.
#define S2R 68
__global__ __launch_bounds__(256) void k3_dcn(
    const uint32_t* __restrict__ y2, const uint32_t* __restrict__ wpo,
    const float* __restrict__ ob,
    const uint32_t* __restrict__ wpk, const float* __restrict__ bn, uint32_t* __restrict__ z2)
{
    __shared__ __align__(16) uint32_t S2[2][32*S2R];   // 17408 B (phase A reuses as 4x1024 fp32)
    __shared__ __align__(16) int   sidx9[9*32*4];      // 4608 B
    __shared__ __align__(16) float swgt9[9*32*4];      // 4608 B
    int blk = blockIdx.x;                  // 1600
    int b = blk / 200, pix0 = (blk % 200) * 32;
    int t = threadIdx.x;
    int lane = t & 63, w = t >> 6;
    int pixl = lane & 31, bhalf = lane >> 5;
    const uint32_t* yb = y2 + (size_t)b*HWX*64;
    floatx16 acc = {};
    int c4 = lane & 31, pixoff = lane >> 5;
    float* LF = (float*)&S2[0][0];

    // ---- phase A: offset-conv pred partials (wave w: taps 2w..2w+1, wave3: 6..8) ----
    {
        floatx16 accp = {};
        int tap0 = (w < 3) ? w*2 : 6;
        int ntap = (w < 3) ? 2 : 3;
        int p = pix0 + pixl;
        int h = p / WID, xw = p % WID;
        for (int tt = 0; tt < ntap; tt++) {
            int tap = tap0 + tt;
            int gh = h + tap/3 - 1, gx = xw + tap%3 - 1;
            bool valid = (gh >= 0) && (gh < HGT) && (gx >= 0) && (gx < WID);
            const uint32_t* pp2 = yb + (size_t)(gh*WID + gx)*64 + bhalf*4;
            const uint32_t* ap = wpo + (size_t)(tap*8)*256 + lane*4;
            #pragma unroll
            for (int s = 0; s < 8; s++) {
                U8 a, bf;
                const uint32_t* as = ap + s*256;
                a.u[0]=as[0]; a.u[1]=as[1]; a.u[2]=as[2]; a.u[3]=as[3];
                if (valid) {
                    uint4 q = *(const uint4*)(pp2 + s*8);
                    bf.u[0]=q.x; bf.u[1]=q.y; bf.u[2]=q.z; bf.u[3]=q.w;
                } else {
                    bf.u[0]=0u; bf.u[1]=0u; bf.u[2]=0u; bf.u[3]=0u;
                }
                accp = __builtin_amdgcn_mfma_f32_32x32x16_bf16(a.s, bf.s, accp, 0, 0, 0);
            }
        }
        #pragma unroll
        for (int r = 0; r < 16; r++) {
            int oc = (r & 3) + 8*(r >> 2) + 4*bhalf;
            LF[w*1024 + oc*32 + pixl] = accp[r];
        }
    }
    __syncthreads();
    // reduce 4 partials + bias; sigmoid mask channels; result in LF[oc*32+px]
    #pragma unroll
    for (int k = 0; k < 4; k++) {
        int e = t + 256*k;
        int oc = e >> 5;
        float v = LF[e] + LF[1024+e] + LF[2048+e] + LF[3072+e];
        if (oc < 27) {
            v += ob[oc];
            if (oc >= 18) v = 1.f/(1.f+__expf(-v));
        }
        LF[e] = v;
    }
    __syncthreads();

    // ---- phase B: bilinear params for all 9 taps (pred from LDS) ----
    for (int it = t; it < 288; it += 256) {
        int tap = it >> 5, px = it & 31;
        int pix = pix0 + px;
        int h = pix / WID, wq = pix % WID;
        float dy = LF[(2*tap)*32 + px];
        float dx = LF[(2*tap+1)*32 + px];
        float mk = LF[(18+tap)*32 + px];
        float pyf = (float)(h - 1 + tap/3) + dy;
        float pxf = (float)(wq - 1 + tap%3) + dx;
        float y0f = floorf(pyf), x0f = floorf(pxf);
        float wy1 = pyf - y0f, wx1 = pxf - x0f;
        int iy0 = (int)y0f, ix0 = (int)x0f;
        int iy1 = iy0 + 1,  ix1 = ix0 + 1;
        float vy0 = (iy0 >= 0 && iy0 < HGT) ? 1.f : 0.f;
        float vy1 = (iy1 >= 0 && iy1 < HGT) ? 1.f : 0.f;
        float vx0 = (ix0 >= 0 && ix0 < WID) ? 1.f : 0.f;
        float vx1 = (ix1 >= 0 && ix1 < WID) ? 1.f : 0.f;
        int cy0 = min(max(iy0,0),HGT-1), cy1 = min(max(iy1,0),HGT-1);
        int cx0 = min(max(ix0,0),WID-1), cx1 = min(max(ix1,0),WID-1);
        int base = (tap*32 + px)*4;
        sidx9[base+0] = cy0*WID+cx0; sidx9[base+1] = cy0*WID+cx1;
        sidx9[base+2] = cy1*WID+cx0; sidx9[base+3] = cy1*WID+cx1;
        swgt9[base+0] = (1.f-wy1)*(1.f-wx1)*mk*vy0*vx0;
        swgt9[base+1] = (1.f-wy1)*wx1*mk*vy0*vx1;
        swgt9[base+2] = wy1*(1.f-wx1)*mk*vy1*vx0;
        swgt9[base+3] = wy1*wx1*mk*vy1*vx1;
    }
    __syncthreads();

    // ---- phase C: main dcn loop ----
    uint2  u[4][4];      // [pass][corner] gathered channel data (this lane's 4 ch)
    float4 W[4];         // [pass] bilinear weights
    uint2  samp[4];      // [pass] packed bf16x2 x2 sampled output

    // prologue gather+compute for tap 0
    #pragma unroll
    for (int p = 0; p < 4; p++) {
        int pix = w*8 + p*2 + pixoff;
        int base = (0*32 + pix)*4;
        int4 si = *(const int4*)&sidx9[base];
        W[p] = *(const float4*)&swgt9[base];
        u[p][0] = *(const uint2*)(yb + (size_t)si.x*64 + c4*2);
        u[p][1] = *(const uint2*)(yb + (size_t)si.y*64 + c4*2);
        u[p][2] = *(const uint2*)(yb + (size_t)si.z*64 + c4*2);
        u[p][3] = *(const uint2*)(yb + (size_t)si.w*64 + c4*2);
    }
    #pragma unroll
    for (int p = 0; p < 4; p++) {
        floatx2 W0, W1, W2, W3;
        W0.x = W0.y = W[p].x; W1.x = W1.y = W[p].y;
        W2.x = W2.y = W[p].z; W3.x = W3.y = W[p].w;
        floatx2 aX = up2(u[p][0].x) * W0;
        aX = __builtin_elementwise_fma(up2(u[p][1].x), W1, aX);
        aX = __builtin_elementwise_fma(up2(u[p][2].x), W2, aX);
        aX = __builtin_elementwise_fma(up2(u[p][3].x), W3, aX);
        floatx2 aY = up2(u[p][0].y) * W0;
        aY = __builtin_elementwise_fma(up2(u[p][1].y), W1, aY);
        aY = __builtin_elementwise_fma(up2(u[p][2].y), W2, aY);
        aY = __builtin_elementwise_fma(up2(u[p][3].y), W3, aY);
        samp[p].x = pk2(aX); samp[p].y = pk2(aY);
    }

    #pragma unroll
    for (int tap = 0; tap < 9; tap++) {
        uint32_t* S = &S2[tap & 1][0];
        #pragma unroll
        for (int p = 0; p < 4; p++) {
            int pix = w*8 + p*2 + pixoff;
            *(uint2*)&S[pix*S2R + c4*2] = samp[p];
        }
        __syncthreads();
        if (tap < 8) {
            #pragma unroll
            for (int p = 0; p < 4; p++) {
                int pix = w*8 + p*2 + pixoff;
                int base = ((tap+1)*32 + pix)*4;
                int4 si = *(const int4*)&sidx9[base];
                W[p] = *(const float4*)&swgt9[base];
                u[p][0] = *(const uint2*)(yb + (size_t)si.x*64 + c4*2);
                u[p][1] = *(const uint2*)(yb + (size_t)si.y*64 + c4*2);
                u[p][2] = *(const uint2*)(yb + (size_t)si.z*64 + c4*2);
                u[p][3] = *(const uint2*)(yb + (size_t)si.w*64 + c4*2);
            }
        }
        const uint32_t* wp = wpk + (size_t)((w*9 + tap)*8)*256 + lane*4;
        #pragma unroll
        for (int s = 0; s < 8; s++) {
            U8 a, bf;
            const uint32_t* wps = wp + s*256;
            a.u[0] = wps[0]; a.u[1] = wps[1]; a.u[2] = wps[2]; a.u[3] = wps[3];
            uint4 q = *(const uint4*)&S[pixl*S2R + s*8 + bhalf*4];
            bf.u[0]=q.x; bf.u[1]=q.y; bf.u[2]=q.z; bf.u[3]=q.w;
            acc = __builtin_amdgcn_mfma_f32_32x32x16_bf16(a.s, bf.s, acc, 0, 0, 0);
        }
        if (tap < 8) {
            #pragma unroll
            for (int p = 0; p < 4; p++) {
                floatx2 W0, W1, W2, W3;
                W0.x = W0.y = W[p].x; W1.x = W1.y = W[p].y;
                W2.x = W2.y = W[p].z; W3.x = W3.y = W[p].w;
                floatx2 aX = up2(u[p][0].x) * W0;
                aX = __builtin_elementwise_fma(up2(u[p][1].x), W1, aX);
                aX = __builtin_elementwise_fma(up2(u[p][2].x), W2, aX);
                aX = __builtin_elementwise_fma(up2(u[p][3].x), W3, aX);
                floatx2 aY = up2(u[p][0].y) * W0;
                aY = __builtin_elementwise_fma(up2(u[p][1].y), W1, aY);
                aY = __builtin_elementwise_fma(up2(u[p][2].y), W2, aY);
                aY = __builtin_elementwise_fma(up2(u[p][3].y), W3, aY);
                samp[p].x = pk2(aX); samp[p].y = pk2(aY);
            }
        }
    }
    // epilogue: BN2+SiLU into S2[1] (tap 8 consumed S2[0])
    uint32_t* SE = &S2[1][0];
    #pragma unroll
    for (int r = 0; r < 16; r += 2) {
        int oc = w*32 + (r & 3) + 8*(r >> 2) + 4*bhalf;
        float s0 = bn[256+oc],   be0 = bn[384+oc];
        float s1 = bn[256+oc+1], be1 = bn[384+oc+1];
        SE[pixl*S2R + (oc >> 1)] = pk2f(silu_f(acc[r]*s0+be0), silu_f(acc[r+1]*s1+be1));
    }
    __syncthreads();
    uint32_t* z2b = z2 + (size_t)b*HWX*64 + (size_t)pix0*64;
    int q2 = t & 31, p0 = t >> 5;
    #pragma unroll
    for (int pp = 0; pp < 4; pp++) {
        int pix = p0 + pp*8;
        uint2 v = *(const uint2*)&SE[pix*S2R + q2*2];
        *(uint2*)(z2b + (size_t)pix*64 + q2*2) = v;
    }
}

// ---------------- k4: conv1x1 (128->256, MFMA) + BN3 + SiLU + residual ----------------
__global__ __launch_bounds__(256) void k4_cv3(
    const uint32_t* __restrict__ z2, const uint32_t* __restrict__ wp3,
    const float* __restrict__ bn, const float* __restrict__ x, float* __restrict__ out)
{
    int blk = blockIdx.x;                  // 1600
    int half = blk & 1, blk2 = blk >> 1;
    int b = blk2 / 100, pix0 = (blk2 % 100) * 64;
    int t = threadIdx.x;
    int lane = t & 63, w = t >> 6;
    int pixl = lane & 31, bhalf = lane >> 5;
    int g = half*4 + w;
    floatx16 acc0 = {}, acc1 = {};
    const uint32_t* zb = z2 + (size_t)b*HWX*64 + (size_t)pix0*64;
    const uint32_t* wpg = wp3 + (size_t)(g*8)*256 + lane*4;

    #pragma unroll
    for (int s = 0; s < 8; s++) {
        U8 a, b0, b1;
        const uint32_t* as = wpg + s*256;
        a.u[0]=as[0]; a.u[1]=as[1]; a.u[2]=as[2]; a.u[3]=as[3];
        uint4 q0 = *(const uint4*)(zb + (size_t)pixl*64 + s*8 + bhalf*4);
        uint4 q1 = *(const uint4*)(zb + (size_t)(32+pixl)*64 + s*8 + bhalf*4);
        b0.u[0]=q0.x; b0.u[1]=q0.y; b0.u[2]=q0.z; b0.u[3]=q0.w;
        b1.u[0]=q1.x; b1.u[1]=q1.y; b1.u[2]=q1.z; b1.u[3]=q1.w;
        acc0 = __builtin_amdgcn_mfma_f32_32x32x16_bf16(a.s, b0.s, acc0, 0, 0, 0);
        acc1 = __builtin_amdgcn_mfma_f32_32x32x16_bf16(a.s, b1.s, acc1, 0, 0, 0);
    }
    const float* xb = x + (size_t)b*COUT*HWX + pix0;
    float* ob = out + (size_t)b*COUT*HWX + pix0;
    #pragma unroll
    for (int r = 0; r < 16; r++) {
        int oc = g*32 + (r & 3) + 8*(r >> 2) + 4*bhalf;
        float sc = bn[512+oc], be = bn[768+oc];
        float v0 = silu_f(acc0[r]*sc+be) + xb[(size_t)oc*HWX + pixl];
        float v1 = silu_f(acc1[r]*sc+be) + xb[(size_t)oc*HWX + 32 + pixl];
        ob[(size_t)oc*HWX + pixl]      = v0;
        ob[(size_t)oc*HWX + 32 + pixl] = v1;
    }
}

extern "C" void kernel_launch(void* const* d_in, const int* in_sizes, int n_in,
                              void* d_out, int out_size, void* d_ws, size_t ws_size,
                              hipStream_t stream) {
    const float* x     = (const float*)d_in[0];
    const float* cv1_w = (const float*)d_in[1];
    const float* bn1_g = (const float*)d_in[2];
    const float* bn1_b = (const float*)d_in[3];
    const float* bn1_m = (const float*)d_in[4];
    const float* bn1_v = (const float*)d_in[5];
    const float* off_w = (const float*)d_in[6];
    const float* off_b = (const float*)d_in[7];
    const float* dcn_w = (const float*)d_in[8];
    const float* dcn_b = (const float*)d_in[9];
    const float* bn2_g = (const float*)d_in[10];
    const float* bn2_b = (const float*)d_in[11];
    const float* bn2_m = (const float*)d_in[12];
    const float* bn2_v = (const float*)d_in[13];
    const float* cv3_w = (const float*)d_in[14];
    const float* bn3_g = (const float*)d_in[15];
    const float* bn3_b = (const float*)d_in[16];
    const float* bn3_m = (const float*)d_in[17];
    const float* bn3_v = (const float*)d_in[18];

    float* ws   = (float*)d_ws;
    float*    BN   = ws + WS_BN;
    uint32_t* Y2   = (uint32_t*)(ws + WS_Y2);
    uint32_t* Z2   = (uint32_t*)(ws + WS_Z2);
    uint32_t* WPK  = (uint32_t*)(ws + WS_WPK);
    uint32_t* WPO  = (uint32_t*)(ws + WS_WPO);
    uint32_t* WP1  = (uint32_t*)(ws + WS_WP1);
    uint32_t* WP3  = (uint32_t*)(ws + WS_WP3);

    hipLaunchKernelGGL(k0_prep, dim3(288), dim3(256), 0, stream,
        dcn_w, off_w, cv1_w, cv3_w,
        bn1_g, bn1_b, bn1_m, bn1_v,
        bn2_g, bn2_b, bn2_m, bn2_v, dcn_b,
        bn3_g, bn3_b, bn3_m, bn3_v, WPK, WPO, WP1, WP3, BN);
    hipLaunchKernelGGL(k1_cv1, dim3(800), dim3(256), 0, stream, x, WP1, BN, Y2);
    hipLaunchKernelGGL(k3_dcn, dim3(1600), dim3(256), 0, stream, Y2, WPO, off_b, WPK, BN, Z2);
    hipLaunchKernelGGL(k4_cv3, dim3(1600), dim3(256), 0, stream, Z2, WP3, BN, x, (float*)d_out);
}